// Round 6
// baseline (203.779 us; speedup 1.0000x reference)
//
#include <hip/hip_runtime.h>
#include <hip/hip_bf16.h>

#define NNODES 100000
#define DIN 128
#define DH 64
#define SRCMASK 0x1FFFF                     // N < 2^17
#define BSH2 8
#define BN2 256                             // nodes per bucket
#define NBUCK2 ((NNODES + BN2 - 1) >> BSH2) // 391
#define NCAP 9088                           // slots per bucket (mean 8192, sigma ~90)
#define EPB 8192                            // edges per block_sort block
#define MAXBLK 512                          // max source blocks (E <= 4.19M)
#define OVFCAP 4096

typedef short s16x8 __attribute__((ext_vector_type(8)));
typedef float f32x4 __attribute__((ext_vector_type(4)));

static __device__ __forceinline__ short f2bf(float f) {
  __hip_bfloat16 h = __float2bfloat16(f);   // RTNE
  return *reinterpret_cast<short*>(&h);
}
static __device__ __forceinline__ float bf2f(short s) {
  return __uint_as_float(((unsigned)(unsigned short)s) << 16);
}

// ---------------- dense transforms via MFMA (hi/lo bf16 split ~ 17-bit mantissa) ----------------
// mfma_f32_16x16x32_bf16 layouts (m89-verified):
//   A: row = lane&15, k = (lane>>4)*8 + i
//   B: col = lane&15, k = (lane>>4)*8 + i
//   D: col = lane&15, row = (lane>>4)*4 + reg

__global__ __launch_bounds__(256, 4) void gemm1_mfma(
    const float* __restrict__ emb, const float* __restrict__ W1,
    __hip_bfloat16* __restrict__ x1, int N) {
  __shared__ short Bhi[4 * 4 * 64 * 8];   // 16 KB
  __shared__ short Blo[4 * 4 * 64 * 8];   // 16 KB
  int tid = threadIdx.x;

  for (int idx = tid; idx < 8192; idx += 256) {
    int i = idx & 7, ln = (idx >> 3) & 63, ct = (idx >> 9) & 3, kc = idx >> 11;
    int k = kc * 32 + (ln >> 4) * 8 + i;
    int col = ct * 16 + (ln & 15);
    float w = W1[k * DH + col];
    short h = f2bf(w);
    Bhi[idx] = h;
    Blo[idx] = f2bf(w - bf2f(h));
  }
  __syncthreads();

  int lane = tid & 63, wv = tid >> 6;
  int r0 = (blockIdx.x * 8 + wv * 2) * 16;   // this wave: rows r0 .. r0+31
  if (r0 >= N) return;

  const int rA = lane & 15, g = lane >> 4;
  f32x4 acc[2][4] = {};

#pragma unroll
  for (int kc = 0; kc < 4; ++kc) {
    s16x8 ahi[2], alo[2];
#pragma unroll
    for (int rt = 0; rt < 2; ++rt) {
      int r = r0 + rt * 16 + rA;
      float av[8];
      if (r < N) {
        const float4* ap = (const float4*)(emb + (long)r * DIN + kc * 32 + g * 8);
        float4 v0 = ap[0], v1 = ap[1];
        av[0] = v0.x; av[1] = v0.y; av[2] = v0.z; av[3] = v0.w;
        av[4] = v1.x; av[5] = v1.y; av[6] = v1.z; av[7] = v1.w;
      } else {
#pragma unroll
        for (int i = 0; i < 8; ++i) av[i] = 0.f;
      }
#pragma unroll
      for (int i = 0; i < 8; ++i) {
        short h = f2bf(av[i]);
        ahi[rt][i] = h;
        alo[rt][i] = f2bf(av[i] - bf2f(h));
      }
    }
#pragma unroll
    for (int ct = 0; ct < 4; ++ct) {
      int fo = ((kc * 4 + ct) * 64 + lane) * 8;
      s16x8 bh = *(const s16x8*)&Bhi[fo];
      s16x8 bl = *(const s16x8*)&Blo[fo];
#pragma unroll
      for (int rt = 0; rt < 2; ++rt) {
        acc[rt][ct] = __builtin_amdgcn_mfma_f32_16x16x32_bf16(ahi[rt], bh, acc[rt][ct], 0, 0, 0);
        acc[rt][ct] = __builtin_amdgcn_mfma_f32_16x16x32_bf16(alo[rt], bh, acc[rt][ct], 0, 0, 0);
        acc[rt][ct] = __builtin_amdgcn_mfma_f32_16x16x32_bf16(ahi[rt], bl, acc[rt][ct], 0, 0, 0);
      }
    }
  }

#pragma unroll
  for (int rt = 0; rt < 2; ++rt) {
#pragma unroll
    for (int j = 0; j < 4; ++j) {
      int row = r0 + rt * 16 + g * 4 + j;
      if (row < N) {
#pragma unroll
        for (int ct = 0; ct < 4; ++ct)
          x1[(long)row * DH + ct * 16 + rA] = __float2bfloat16(acc[rt][ct][j]);
      }
    }
  }
}

__global__ __launch_bounds__(256, 4) void gemm2_mfma(
    const float* __restrict__ agg, const float* __restrict__ W2,
    const float* __restrict__ b1, __hip_bfloat16* __restrict__ x2, int N) {
  __shared__ short Bhi[2 * 4 * 64 * 8];   // 8 KB
  __shared__ short Blo[2 * 4 * 64 * 8];   // 8 KB
  int tid = threadIdx.x;

  for (int idx = tid; idx < 4096; idx += 256) {
    int i = idx & 7, ln = (idx >> 3) & 63, ct = (idx >> 9) & 3, kc = (idx >> 11) & 1;
    int k = kc * 32 + (ln >> 4) * 8 + i;
    int col = ct * 16 + (ln & 15);
    float w = W2[k * DH + col];
    short h = f2bf(w);
    Bhi[idx] = h;
    Blo[idx] = f2bf(w - bf2f(h));
  }
  __syncthreads();

  int lane = tid & 63, wv = tid >> 6;
  int r0 = (blockIdx.x * 8 + wv * 2) * 16;
  if (r0 >= N) return;

  const int rA = lane & 15, g = lane >> 4;
  f32x4 acc[2][4] = {};

#pragma unroll
  for (int kc = 0; kc < 2; ++kc) {
    const float4* bp = (const float4*)(b1 + kc * 32 + g * 8);
    float4 b0 = bp[0], b4 = bp[1];
    float bv[8] = {b0.x, b0.y, b0.z, b0.w, b4.x, b4.y, b4.z, b4.w};
    s16x8 ahi[2], alo[2];
#pragma unroll
    for (int rt = 0; rt < 2; ++rt) {
      int r = r0 + rt * 16 + rA;
      float av[8];
      if (r < N) {
        const float4* ap = (const float4*)(agg + (long)r * DH + kc * 32 + g * 8);
        float4 v0 = ap[0], v1 = ap[1];
        av[0] = v0.x; av[1] = v0.y; av[2] = v0.z; av[3] = v0.w;
        av[4] = v1.x; av[5] = v1.y; av[6] = v1.z; av[7] = v1.w;
      } else {
#pragma unroll
        for (int i = 0; i < 8; ++i) av[i] = -1e30f;  // relu() -> 0 anyway
      }
#pragma unroll
      for (int i = 0; i < 8; ++i) {
        float a = fmaxf(av[i] + bv[i], 0.f);
        short h = f2bf(a);
        ahi[rt][i] = h;
        alo[rt][i] = f2bf(a - bf2f(h));
      }
    }
#pragma unroll
    for (int ct = 0; ct < 4; ++ct) {
      int fo = ((kc * 4 + ct) * 64 + lane) * 8;
      s16x8 bh = *(const s16x8*)&Bhi[fo];
      s16x8 bl = *(const s16x8*)&Blo[fo];
#pragma unroll
      for (int rt = 0; rt < 2; ++rt) {
        acc[rt][ct] = __builtin_amdgcn_mfma_f32_16x16x32_bf16(ahi[rt], bh, acc[rt][ct], 0, 0, 0);
        acc[rt][ct] = __builtin_amdgcn_mfma_f32_16x16x32_bf16(alo[rt], bh, acc[rt][ct], 0, 0, 0);
        acc[rt][ct] = __builtin_amdgcn_mfma_f32_16x16x32_bf16(ahi[rt], bl, acc[rt][ct], 0, 0, 0);
      }
    }
  }

#pragma unroll
  for (int rt = 0; rt < 2; ++rt) {
#pragma unroll
    for (int j = 0; j < 4; ++j) {
      int row = r0 + rt * 16 + g * 4 + j;
      if (row < N) {
#pragma unroll
        for (int ct = 0; ct < 4; ++ct)
          x2[(long)row * DH + ct * 16 + rA] = __float2bfloat16(acc[rt][ct][j]);
      }
    }
  }
}

// ---------------- 2-pass counting-sort build, all global writes coalesced ----------------

__global__ __launch_bounds__(512) void block_sort(
    const int* __restrict__ srcs, const int* __restrict__ dsts,
    const float* __restrict__ w, int2* __restrict__ sorted,
    unsigned short* __restrict__ offTab, int E) {
  __shared__ int2 stage[EPB];      // 64 KB
  __shared__ int hist[512];
  __shared__ int sc[512];
  __shared__ int cur[512];
  int tid = threadIdx.x, blk = blockIdx.x;
  int e0 = blk * EPB;

  hist[tid] = 0;
  __syncthreads();

  int pk[16], bd[16];
#pragma unroll
  for (int i = 0; i < 16; ++i) {
    int e = e0 + i * 512 + tid;
    if (e < E) {
      int s = srcs[e], d = dsts[e];
      float wv = w[e];
      int q = (int)(wv * 32768.f + 0.5f);
      if (q > 32767) q = 32767;
      pk[i] = (s & SRCMASK) | (q << 17);
      bd[i] = d;
    } else bd[i] = -1;
  }
#pragma unroll
  for (int i = 0; i < 16; ++i)
    if (bd[i] >= 0) atomicAdd(&hist[bd[i] >> BSH2], 1);
  __syncthreads();

  sc[tid] = (tid < NBUCK2) ? hist[tid] : 0;
  __syncthreads();
  for (int d = 1; d < 512; d <<= 1) {
    int u = (tid >= d) ? sc[tid - d] : 0;
    __syncthreads();
    sc[tid] += u;
    __syncthreads();
  }
  long row = (long)blk * (NBUCK2 + 1);
  if (tid < NBUCK2) {
    int base = sc[tid] - hist[tid];
    cur[tid] = base;
    offTab[row + tid] = (unsigned short)base;
    if (tid == NBUCK2 - 1) offTab[row + NBUCK2] = (unsigned short)sc[tid];
  }
  __syncthreads();

#pragma unroll
  for (int i = 0; i < 16; ++i) {
    if (bd[i] >= 0) {
      int pos = atomicAdd(&cur[bd[i] >> BSH2], 1);
      stage[pos] = make_int2(pk[i], bd[i] & (BN2 - 1));
    }
  }
  __syncthreads();

  int eN = min(EPB, E - e0);
  for (int i = tid; i < eN; i += 512)
    sorted[(long)blk * EPB + i] = stage[i];   // fully coalesced
}

__global__ __launch_bounds__(512) void gather_build(
    const unsigned short* __restrict__ offTab, const int2* __restrict__ sorted,
    int* __restrict__ noff, int* __restrict__ ndeg, int* __restrict__ pairs,
    int2* __restrict__ ovf, int* __restrict__ ovfcnt, int NBLK, int N) {
  __shared__ int2 gath[NCAP];             // 71 KB
  __shared__ unsigned short offR[MAXBLK]; // 1 KB
  __shared__ unsigned short cntR[MAXBLK]; // 1 KB
  __shared__ int baseR[MAXBLK];           // 2 KB
  __shared__ int sc[512];                 // 2 KB
  __shared__ int deg[BN2], cur[BN2];      // 2 KB
  int b = blockIdx.x, tid = threadIdx.x;

  for (int blk = tid; blk < NBLK; blk += 512) {
    long row = (long)blk * (NBUCK2 + 1);
    int st = offTab[row + b];
    int en = offTab[row + b + 1];
    offR[blk] = (unsigned short)st;
    cntR[blk] = (unsigned short)(en - st);
  }
  __syncthreads();

  sc[tid] = (tid < NBLK) ? (int)cntR[tid] : 0;
  __syncthreads();
  for (int d = 1; d < 512; d <<= 1) {
    int u = (tid >= d) ? sc[tid - d] : 0;
    __syncthreads();
    sc[tid] += u;
    __syncthreads();
  }
  if (tid < NBLK) baseR[tid] = sc[tid] - (int)cntR[tid];
  __syncthreads();
  int total = sc[NBLK - 1];
  int tcl = total > NCAP ? NCAP : total;

  int wv = tid >> 6, lane = tid & 63;
  for (int blk = wv; blk < NBLK; blk += 8) {
    int st = offR[blk], c = cntR[blk], gb = baseR[blk];
    for (int l = lane; l < c; l += 64) {
      int2 v = sorted[(long)blk * EPB + st + l];
      int gp = gb + l;
      if (gp < NCAP) gath[gp] = v;
      else {
        int oi = atomicAdd(ovfcnt, 1);
        if (oi < OVFCAP) ovf[oi] = make_int2(v.x, (b << BSH2) | v.y);
      }
    }
  }
  if (tid < BN2) deg[tid] = 0;
  __syncthreads();

  for (int k = tid; k < tcl; k += 512)
    atomicAdd(&deg[gath[k].y & (BN2 - 1)], 1);
  __syncthreads();

  sc[tid] = (tid < BN2) ? deg[tid] : 0;
  __syncthreads();
  for (int d = 1; d < 512; d <<= 1) {
    int u = (tid >= d) ? sc[tid - d] : 0;
    __syncthreads();
    sc[tid] += u;
    __syncthreads();
  }
  if (tid < BN2) {
    int excl = sc[tid] - deg[tid];
    int gpos = b * NCAP + excl;
    cur[tid] = gpos;
    int n = (b << BSH2) + tid;
    if (n < N) { noff[n] = gpos; ndeg[n] = deg[tid]; }
  }
  __syncthreads();

  for (int k = tid; k < tcl; k += 512) {
    int p = atomicAdd(&cur[gath[k].y & (BN2 - 1)], 1);
    pairs[p] = gath[k].x;
  }
}

__global__ __launch_bounds__(256) void ovf_fixup(
    const int2* __restrict__ ovf, const int* __restrict__ ovfcnt,
    const short* __restrict__ x, float* __restrict__ out) {
  int cnt = *ovfcnt;
  if (cnt > OVFCAP) cnt = OVFCAP;
  int wid = (int)((blockIdx.x * 256 + threadIdx.x) >> 6);
  int lane = threadIdx.x & 63;
  int nw = (gridDim.x * 256) >> 6;
  for (int i = wid; i < cnt; i += nw) {
    int2 e = ovf[i];
    unsigned p = (unsigned)e.x;
    float wv = (float)(p >> 17) * (1.f / 32768.f);
    float xv = bf2f(x[(long)(p & SRCMASK) * DH + lane]);
    atomicAdd(&out[(long)e.y * DH + lane], wv * xv);
  }
}

// ---------------- aggregation: 4 nodes/wave, cross-node software pipeline ----------------
// lane = h*16 + fj : h = edge-of-quad (0..3), fj = feature-quad (0..15).
// All 4 pairs-row loads issue up front; iteration j issues node j+1's gathers and
// node j's batch-2 gathers (deg>32) BEFORE accumulating node j's batch-1, hiding
// gather latency under the previous node's FMA work. Padded lanes hold 0 => w=0.
#define ACC4(P, XV)                                          \
  do {                                                       \
    float wv_ = (float)((P) >> 17) * (1.f / 32768.f);        \
    a0 += wv_ * __uint_as_float((XV).x << 16);               \
    a1 += wv_ * __uint_as_float((XV).x & 0xFFFF0000u);       \
    a2 += wv_ * __uint_as_float((XV).y << 16);               \
    a3 += wv_ * __uint_as_float((XV).y & 0xFFFF0000u);       \
  } while (0)

__global__ __launch_bounds__(256) void agg_quad(
    const int* __restrict__ pairs, const int* __restrict__ noff,
    const int* __restrict__ ndeg,
    const uint2* __restrict__ x,   // 4×bf16 per element, 16 per node
    const float* __restrict__ bias, float* __restrict__ out, int N) {
  int wv = (int)(((long)blockIdx.x * 256 + threadIdx.x) >> 6);
  int lane = threadIdx.x & 63;
  int h = lane >> 4;        // edge within quad
  int fj = lane & 15;       // feature-quad index
  int n0 = wv * 4;
  if (n0 >= N) return;

  int pl[4], st[4], m[4];
#pragma unroll
  for (int j = 0; j < 4; ++j) {
    int n = n0 + j;
    st[j] = (n < N) ? noff[n] : 0;
    m[j]  = (n < N) ? ndeg[n] : 0;
  }
#pragma unroll
  for (int j = 0; j < 4; ++j)
    pl[j] = (lane < m[j]) ? pairs[st[j] + lane] : 0;   // 4 coalesced loads in flight

  // prologue: node 0 batch-1 gathers
  unsigned pgA[8], pgB[8], pgC[8];
  uint2 xgA[8], xgB[8], xgC[8];
#pragma unroll
  for (int g = 0; g < 8; ++g) pgA[g] = (unsigned)__shfl(pl[0], g * 4 + h);
#pragma unroll
  for (int g = 0; g < 8; ++g) xgA[g] = x[(pgA[g] & SRCMASK) * 16 + fj];

#pragma unroll
  for (int j = 0; j < 4; ++j) {
    // issue next node's batch-1 gathers
    if (j + 1 < 4) {
#pragma unroll
      for (int g = 0; g < 8; ++g) pgB[g] = (unsigned)__shfl(pl[j + 1], g * 4 + h);
#pragma unroll
      for (int g = 0; g < 8; ++g) xgB[g] = x[(pgB[g] & SRCMASK) * 16 + fj];
    }
    // issue this node's batch-2 gathers (edges 32..63); padded lanes are 0
    bool big = (m[j] > 32);
    if (big) {
#pragma unroll
      for (int g = 0; g < 8; ++g) pgC[g] = (unsigned)__shfl(pl[j], 32 + g * 4 + h);
#pragma unroll
      for (int g = 0; g < 8; ++g) xgC[g] = x[(pgC[g] & SRCMASK) * 16 + fj];
    }

    float a0 = 0.f, a1 = 0.f, a2 = 0.f, a3 = 0.f;
#pragma unroll
    for (int g = 0; g < 8; ++g) ACC4(pgA[g], xgA[g]);
    if (big) {
#pragma unroll
      for (int g = 0; g < 8; ++g) ACC4(pgC[g], xgC[g]);
    }

    // rare correctness tail: deg > 64
    if (m[j] > 64) {
      for (int base = 64; base < m[j]; base += 64) {
        int pls = (base + lane < m[j]) ? pairs[st[j] + base + lane] : 0;
        int mm = m[j] - base;
        for (int q = 0; q < 64; q += 16) {
          if (q >= mm) break;
          unsigned p0 = (unsigned)__shfl(pls, q + h);
          unsigned p1 = (unsigned)__shfl(pls, q + 4 + h);
          unsigned p2 = (unsigned)__shfl(pls, q + 8 + h);
          unsigned p3 = (unsigned)__shfl(pls, q + 12 + h);
          uint2 y0 = x[(p0 & SRCMASK) * 16 + fj];
          uint2 y1 = x[(p1 & SRCMASK) * 16 + fj];
          uint2 y2 = x[(p2 & SRCMASK) * 16 + fj];
          uint2 y3 = x[(p3 & SRCMASK) * 16 + fj];
          ACC4(p0, y0); ACC4(p1, y1); ACC4(p2, y2); ACC4(p3, y3);
        }
      }
    }

    // reduce over the 4 edge-groups (h) and store node j
    a0 += __shfl_xor(a0, 16); a0 += __shfl_xor(a0, 32);
    a1 += __shfl_xor(a1, 16); a1 += __shfl_xor(a1, 32);
    a2 += __shfl_xor(a2, 16); a2 += __shfl_xor(a2, 32);
    a3 += __shfl_xor(a3, 16); a3 += __shfl_xor(a3, 32);
    if (lane < 16 && n0 + j < N) {
      if (bias) {
        float4 bv = ((const float4*)bias)[fj];
        a0 += bv.x; a1 += bv.y; a2 += bv.z; a3 += bv.w;
      }
      ((float4*)out)[(long)(n0 + j) * 16 + fj] = make_float4(a0, a1, a2, a3);
    }

    // rotate pipeline B -> A
    if (j + 1 < 4) {
#pragma unroll
      for (int g = 0; g < 8; ++g) { pgA[g] = pgB[g]; xgA[g] = xgB[g]; }
    }
  }
}

// ---------------- fallback kernels (R1 atomic path, f32) ----------------

__global__ __launch_bounds__(256) void gemm1_f32(
    const float* __restrict__ emb, const float* __restrict__ W1,
    float* __restrict__ x1, int N) {
  __shared__ float Ws[DIN * DH];
  __shared__ float rows[4][DIN];
  int tid = threadIdx.x;
  for (int i = tid; i < DIN * DH; i += 256) Ws[i] = W1[i];
  int r0 = blockIdx.x * 4;
  for (int i = tid; i < 4 * DIN; i += 256) {
    int rr = i >> 7, kk = i & 127;
    int r = r0 + rr;
    rows[rr][kk] = (r < N) ? emb[(long)r * DIN + kk] : 0.f;
  }
  __syncthreads();
  int rr = tid >> 6, j = tid & 63;
  int r = r0 + rr;
  float acc = 0.f;
#pragma unroll
  for (int k = 0; k < DIN; ++k) acc += rows[rr][k] * Ws[k * DH + j];
  if (r < N) x1[(long)r * DH + j] = acc;
}

__global__ __launch_bounds__(256) void gemm2_f32(
    const float* __restrict__ agg, const float* __restrict__ W2,
    const float* __restrict__ b1, float* __restrict__ x2, int N) {
  __shared__ float Ws[DH * DH];
  __shared__ float rows[4][DH];
  int tid = threadIdx.x;
  for (int i = tid; i < DH * DH; i += 256) Ws[i] = W2[i];
  int r0 = blockIdx.x * 4;
  {
    int rr = tid >> 6, kk = tid & 63;
    int r = r0 + rr;
    float v = (r < N) ? agg[(long)r * DH + kk] + b1[kk] : 0.f;
    rows[rr][kk] = v > 0.f ? v : 0.f;
  }
  __syncthreads();
  int rr = tid >> 6, j = tid & 63;
  float acc = 0.f;
#pragma unroll
  for (int k = 0; k < DH; ++k) acc += rows[rr][k] * Ws[k * DH + j];
  int r = r0 + rr;
  if (r < N) x2[(long)r * DH + j] = acc;
}

__global__ __launch_bounds__(256) void init_bias_kernel(
    float* __restrict__ out, const float* __restrict__ b2, int total) {
  int i = blockIdx.x * 256 + threadIdx.x;
  if (i < total) out[i] = b2[i & 63];
}

__global__ __launch_bounds__(256) void scatter_kernel(
    const int* __restrict__ srcs, const int* __restrict__ dsts,
    const float* __restrict__ w, const float* __restrict__ x,
    float* __restrict__ out, int E) {
  long t = (long)blockIdx.x * 256 + threadIdx.x;
  long e = t >> 6;
  if (e >= E) return;
  int j = (int)(t & 63);
  int s = srcs[e];
  int d = dsts[e];
  float val = w[e] * x[(long)s * DH + j];
  atomicAdd(&out[(long)d * DH + j], val);
}

// ---------------- host ----------------

static inline size_t align256(size_t x) { return (x + 255) & ~(size_t)255; }

extern "C" void kernel_launch(void* const* d_in, const int* in_sizes, int n_in,
                              void* d_out, int out_size, void* d_ws, size_t ws_size,
                              hipStream_t stream) {
  const int*   edge_index = (const int*)d_in[0];
  const float* edge_w     = (const float*)d_in[1];
  const float* emb        = (const float*)d_in[2];
  const float* W1         = (const float*)d_in[3];
  const float* b1         = (const float*)d_in[4];
  const float* W2         = (const float*)d_in[5];
  const float* b2         = (const float*)d_in[6];
  float* out = (float*)d_out;

  const int E = in_sizes[0] / 2;
  const int N = NNODES;
  const int* srcs = edge_index;
  const int* dsts = edge_index + E;

  const int NBLK = (E + EPB - 1) / EPB;     // 391 for E = 3.2M

  const size_t sortedbytes = (size_t)NBLK * EPB * sizeof(int2);         // 25.6 MB
  const size_t xbytes_bf   = (size_t)N * DH * sizeof(__hip_bfloat16);   // 12.8 MB
  const size_t offTabbytes = (size_t)NBLK * (NBUCK2 + 1) * sizeof(unsigned short);
  const size_t pairsbytes  = (size_t)NBUCK2 * NCAP * sizeof(int);       // 14.2 MB
  const size_t nbytes      = (size_t)N * sizeof(int);

  const int aggBlocks = (N + 15) / 16;      // 4 waves/block x 4 nodes/wave
  const int gemmBlocks = (N + 127) / 128;   // 128 rows per block (4 waves x 32 rows)

  size_t off = 0;
  char* base = (char*)d_ws;
  int2* sorted = (int2*)(base + off);
  off = align256(off + (sortedbytes > xbytes_bf ? sortedbytes : xbytes_bf));
  __hip_bfloat16* xbuf = (__hip_bfloat16*)sorted;  // alias: sorted dead after gather_build
  unsigned short* offTab = (unsigned short*)(base + off); off = align256(off + offTabbytes);
  int* pairs = (int*)(base + off);  off = align256(off + pairsbytes);
  int* noff  = (int*)(base + off);  off = align256(off + nbytes);
  int* ndeg  = (int*)(base + off);  off = align256(off + nbytes);
  int2* ovf  = (int2*)(base + off); off = align256(off + OVFCAP * sizeof(int2));
  int* ovfcnt = (int*)(base + off); off = align256(off + 256);
  const size_t needed_full = off;

  if (ws_size >= needed_full && NBLK <= MAXBLK) {
    // ---- 2-pass coalesced counting-sort build (once, reused by both layers) ----
    hipMemsetAsync(ovfcnt, 0, sizeof(int), stream);
    block_sort<<<NBLK, 512, 0, stream>>>(srcs, dsts, edge_w, sorted, offTab, E);
    gather_build<<<NBUCK2, 512, 0, stream>>>(offTab, sorted, noff, ndeg, pairs,
                                             ovf, ovfcnt, NBLK, N);

    // ---- layer 1: x1 = bf16(emb@W1); agg1 = A@x1 (into d_out, f32) ----
    gemm1_mfma<<<gemmBlocks, 256, 0, stream>>>(emb, W1, xbuf, N);
    agg_quad<<<aggBlocks, 256, 0, stream>>>(pairs, noff, ndeg, (const uint2*)xbuf,
                                            nullptr, out, N);
    ovf_fixup<<<8, 256, 0, stream>>>(ovf, ovfcnt, (const short*)xbuf, out);

    // ---- layer 2: x2 = bf16(relu(agg1+b1)@W2); out = A@x2 + b2 ----
    gemm2_mfma<<<gemmBlocks, 256, 0, stream>>>(out, W2, b1, xbuf, N);
    agg_quad<<<aggBlocks, 256, 0, stream>>>(pairs, noff, ndeg, (const uint2*)xbuf,
                                            b2, out, N);
    ovf_fixup<<<8, 256, 0, stream>>>(ovf, ovfcnt, (const short*)xbuf, out);
    return;
  }

  // ---- R1 fallback: atomic scatter (needs only N*64 f32) ----
  const long scatterThreads = (long)E * 64;
  const int scatterBlocks = (int)((scatterThreads + 255) / 256);
  const int rowBlocks4 = (N + 3) / 4;
  float* xb1 = (float*)d_ws;

  gemm1_f32<<<rowBlocks4, 256, 0, stream>>>(emb, W1, xb1, N);
  hipMemsetAsync(d_out, 0, (size_t)N * DH * sizeof(float), stream);
  scatter_kernel<<<scatterBlocks, 256, 0, stream>>>(srcs, dsts, edge_w, xb1, out, E);

  gemm2_f32<<<rowBlocks4, 256, 0, stream>>>(out, W2, b1, xb1, N);
  init_bias_kernel<<<(N * DH + 255) / 256, 256, 0, stream>>>(out, b2, N * DH);
  scatter_kernel<<<scatterBlocks, 256, 0, stream>>>(srcs, dsts, edge_w, xb1, out, E);
}

// Round 7
// 200.813 us; speedup vs baseline: 1.0148x; 1.0148x over previous
//
#include <hip/hip_runtime.h>
#include <hip/hip_bf16.h>

#define NNODES 100000
#define DIN 128
#define DH 64
#define SRCMASK 0x1FFFF                     // N < 2^17
#define BSH2 8
#define BN2 256                             // nodes per bucket
#define NBUCK2 ((NNODES + BN2 - 1) >> BSH2) // 391
#define NCAP 9088                           // slots per bucket (mean 8192, sigma ~90)
#define EPB 8192                            // edges per block_sort block
#define MAXBLK 512                          // max source blocks (E <= 4.19M)
#define OVFCAP 4096

typedef short s16x8 __attribute__((ext_vector_type(8)));
typedef float f32x4 __attribute__((ext_vector_type(4)));

static __device__ __forceinline__ short f2bf(float f) {
  __hip_bfloat16 h = __float2bfloat16(f);   // RTNE
  return *reinterpret_cast<short*>(&h);
}
static __device__ __forceinline__ float bf2f(short s) {
  return __uint_as_float(((unsigned)(unsigned short)s) << 16);
}

// ---------------- dense transforms via MFMA (hi/lo bf16 split ~ 17-bit mantissa) ----------------
// mfma_f32_16x16x32_bf16 layouts (m89-verified):
//   A: row = lane&15, k = (lane>>4)*8 + i
//   B: col = lane&15, k = (lane>>4)*8 + i
//   D: col = lane&15, row = (lane>>4)*4 + reg

__global__ __launch_bounds__(256, 4) void gemm1_mfma(
    const float* __restrict__ emb, const float* __restrict__ W1,
    __hip_bfloat16* __restrict__ x1, int N) {
  __shared__ short Bhi[4 * 4 * 64 * 8];   // 16 KB
  __shared__ short Blo[4 * 4 * 64 * 8];   // 16 KB
  int tid = threadIdx.x;

  for (int idx = tid; idx < 8192; idx += 256) {
    int i = idx & 7, ln = (idx >> 3) & 63, ct = (idx >> 9) & 3, kc = idx >> 11;
    int k = kc * 32 + (ln >> 4) * 8 + i;
    int col = ct * 16 + (ln & 15);
    float w = W1[k * DH + col];
    short h = f2bf(w);
    Bhi[idx] = h;
    Blo[idx] = f2bf(w - bf2f(h));
  }
  __syncthreads();

  int lane = tid & 63, wv = tid >> 6;
  int r0 = (blockIdx.x * 8 + wv * 2) * 16;   // this wave: rows r0 .. r0+31
  if (r0 >= N) return;

  const int rA = lane & 15, g = lane >> 4;
  f32x4 acc[2][4] = {};

#pragma unroll
  for (int kc = 0; kc < 4; ++kc) {
    s16x8 ahi[2], alo[2];
#pragma unroll
    for (int rt = 0; rt < 2; ++rt) {
      int r = r0 + rt * 16 + rA;
      float av[8];
      if (r < N) {
        const float4* ap = (const float4*)(emb + (long)r * DIN + kc * 32 + g * 8);
        float4 v0 = ap[0], v1 = ap[1];
        av[0] = v0.x; av[1] = v0.y; av[2] = v0.z; av[3] = v0.w;
        av[4] = v1.x; av[5] = v1.y; av[6] = v1.z; av[7] = v1.w;
      } else {
#pragma unroll
        for (int i = 0; i < 8; ++i) av[i] = 0.f;
      }
#pragma unroll
      for (int i = 0; i < 8; ++i) {
        short h = f2bf(av[i]);
        ahi[rt][i] = h;
        alo[rt][i] = f2bf(av[i] - bf2f(h));
      }
    }
#pragma unroll
    for (int ct = 0; ct < 4; ++ct) {
      int fo = ((kc * 4 + ct) * 64 + lane) * 8;
      s16x8 bh = *(const s16x8*)&Bhi[fo];
      s16x8 bl = *(const s16x8*)&Blo[fo];
#pragma unroll
      for (int rt = 0; rt < 2; ++rt) {
        acc[rt][ct] = __builtin_amdgcn_mfma_f32_16x16x32_bf16(ahi[rt], bh, acc[rt][ct], 0, 0, 0);
        acc[rt][ct] = __builtin_amdgcn_mfma_f32_16x16x32_bf16(alo[rt], bh, acc[rt][ct], 0, 0, 0);
        acc[rt][ct] = __builtin_amdgcn_mfma_f32_16x16x32_bf16(ahi[rt], bl, acc[rt][ct], 0, 0, 0);
      }
    }
  }

#pragma unroll
  for (int rt = 0; rt < 2; ++rt) {
#pragma unroll
    for (int j = 0; j < 4; ++j) {
      int row = r0 + rt * 16 + g * 4 + j;
      if (row < N) {
#pragma unroll
        for (int ct = 0; ct < 4; ++ct)
          x1[(long)row * DH + ct * 16 + rA] = __float2bfloat16(acc[rt][ct][j]);
      }
    }
  }
}

__global__ __launch_bounds__(256, 4) void gemm2_mfma(
    const float* __restrict__ agg, const float* __restrict__ W2,
    const float* __restrict__ b1, __hip_bfloat16* __restrict__ x2, int N) {
  __shared__ short Bhi[2 * 4 * 64 * 8];   // 8 KB
  __shared__ short Blo[2 * 4 * 64 * 8];   // 8 KB
  int tid = threadIdx.x;

  for (int idx = tid; idx < 4096; idx += 256) {
    int i = idx & 7, ln = (idx >> 3) & 63, ct = (idx >> 9) & 3, kc = (idx >> 11) & 1;
    int k = kc * 32 + (ln >> 4) * 8 + i;
    int col = ct * 16 + (ln & 15);
    float w = W2[k * DH + col];
    short h = f2bf(w);
    Bhi[idx] = h;
    Blo[idx] = f2bf(w - bf2f(h));
  }
  __syncthreads();

  int lane = tid & 63, wv = tid >> 6;
  int r0 = (blockIdx.x * 8 + wv * 2) * 16;
  if (r0 >= N) return;

  const int rA = lane & 15, g = lane >> 4;
  f32x4 acc[2][4] = {};

#pragma unroll
  for (int kc = 0; kc < 2; ++kc) {
    const float4* bp = (const float4*)(b1 + kc * 32 + g * 8);
    float4 b0 = bp[0], b4 = bp[1];
    float bv[8] = {b0.x, b0.y, b0.z, b0.w, b4.x, b4.y, b4.z, b4.w};
    s16x8 ahi[2], alo[2];
#pragma unroll
    for (int rt = 0; rt < 2; ++rt) {
      int r = r0 + rt * 16 + rA;
      float av[8];
      if (r < N) {
        const float4* ap = (const float4*)(agg + (long)r * DH + kc * 32 + g * 8);
        float4 v0 = ap[0], v1 = ap[1];
        av[0] = v0.x; av[1] = v0.y; av[2] = v0.z; av[3] = v0.w;
        av[4] = v1.x; av[5] = v1.y; av[6] = v1.z; av[7] = v1.w;
      } else {
#pragma unroll
        for (int i = 0; i < 8; ++i) av[i] = -1e30f;  // relu() -> 0 anyway
      }
#pragma unroll
      for (int i = 0; i < 8; ++i) {
        float a = fmaxf(av[i] + bv[i], 0.f);
        short h = f2bf(a);
        ahi[rt][i] = h;
        alo[rt][i] = f2bf(a - bf2f(h));
      }
    }
#pragma unroll
    for (int ct = 0; ct < 4; ++ct) {
      int fo = ((kc * 4 + ct) * 64 + lane) * 8;
      s16x8 bh = *(const s16x8*)&Bhi[fo];
      s16x8 bl = *(const s16x8*)&Blo[fo];
#pragma unroll
      for (int rt = 0; rt < 2; ++rt) {
        acc[rt][ct] = __builtin_amdgcn_mfma_f32_16x16x32_bf16(ahi[rt], bh, acc[rt][ct], 0, 0, 0);
        acc[rt][ct] = __builtin_amdgcn_mfma_f32_16x16x32_bf16(alo[rt], bh, acc[rt][ct], 0, 0, 0);
        acc[rt][ct] = __builtin_amdgcn_mfma_f32_16x16x32_bf16(ahi[rt], bl, acc[rt][ct], 0, 0, 0);
      }
    }
  }

#pragma unroll
  for (int rt = 0; rt < 2; ++rt) {
#pragma unroll
    for (int j = 0; j < 4; ++j) {
      int row = r0 + rt * 16 + g * 4 + j;
      if (row < N) {
#pragma unroll
        for (int ct = 0; ct < 4; ++ct)
          x2[(long)row * DH + ct * 16 + rA] = __float2bfloat16(acc[rt][ct][j]);
      }
    }
  }
}

// ---------------- 2-pass counting-sort build, all global writes coalesced ----------------

__global__ __launch_bounds__(512) void block_sort(
    const int* __restrict__ srcs, const int* __restrict__ dsts,
    const float* __restrict__ w, int2* __restrict__ sorted,
    unsigned short* __restrict__ offTab, int E) {
  __shared__ int2 stage[EPB];      // 64 KB
  __shared__ int hist[512];
  __shared__ int sc[512];
  __shared__ int cur[512];
  int tid = threadIdx.x, blk = blockIdx.x;
  int e0 = blk * EPB;

  hist[tid] = 0;
  __syncthreads();

  int pk[16], bd[16];
#pragma unroll
  for (int i = 0; i < 16; ++i) {
    int e = e0 + i * 512 + tid;
    if (e < E) {
      int s = srcs[e], d = dsts[e];
      float wv = w[e];
      int q = (int)(wv * 32768.f + 0.5f);
      if (q > 32767) q = 32767;
      pk[i] = (s & SRCMASK) | (q << 17);
      bd[i] = d;
    } else bd[i] = -1;
  }
#pragma unroll
  for (int i = 0; i < 16; ++i)
    if (bd[i] >= 0) atomicAdd(&hist[bd[i] >> BSH2], 1);
  __syncthreads();

  sc[tid] = (tid < NBUCK2) ? hist[tid] : 0;
  __syncthreads();
  for (int d = 1; d < 512; d <<= 1) {
    int u = (tid >= d) ? sc[tid - d] : 0;
    __syncthreads();
    sc[tid] += u;
    __syncthreads();
  }
  long row = (long)blk * (NBUCK2 + 1);
  if (tid < NBUCK2) {
    int base = sc[tid] - hist[tid];
    cur[tid] = base;
    offTab[row + tid] = (unsigned short)base;
    if (tid == NBUCK2 - 1) offTab[row + NBUCK2] = (unsigned short)sc[tid];
  }
  __syncthreads();

#pragma unroll
  for (int i = 0; i < 16; ++i) {
    if (bd[i] >= 0) {
      int pos = atomicAdd(&cur[bd[i] >> BSH2], 1);
      stage[pos] = make_int2(pk[i], bd[i] & (BN2 - 1));
    }
  }
  __syncthreads();

  int eN = min(EPB, E - e0);
  for (int i = tid; i < eN; i += 512)
    sorted[(long)blk * EPB + i] = stage[i];   // fully coalesced
}

__global__ __launch_bounds__(512) void gather_build(
    const unsigned short* __restrict__ offTab, const int2* __restrict__ sorted,
    int* __restrict__ noff, int* __restrict__ ndeg, int* __restrict__ pairs,
    int2* __restrict__ ovf, int* __restrict__ ovfcnt, int NBLK, int N) {
  __shared__ int2 gath[NCAP];             // 71 KB
  __shared__ unsigned short offR[MAXBLK]; // 1 KB
  __shared__ unsigned short cntR[MAXBLK]; // 1 KB
  __shared__ int baseR[MAXBLK];           // 2 KB
  __shared__ int sc[512];                 // 2 KB
  __shared__ int deg[BN2], cur[BN2];      // 2 KB
  int b = blockIdx.x, tid = threadIdx.x;

  for (int blk = tid; blk < NBLK; blk += 512) {
    long row = (long)blk * (NBUCK2 + 1);
    int st = offTab[row + b];
    int en = offTab[row + b + 1];
    offR[blk] = (unsigned short)st;
    cntR[blk] = (unsigned short)(en - st);
  }
  __syncthreads();

  sc[tid] = (tid < NBLK) ? (int)cntR[tid] : 0;
  __syncthreads();
  for (int d = 1; d < 512; d <<= 1) {
    int u = (tid >= d) ? sc[tid - d] : 0;
    __syncthreads();
    sc[tid] += u;
    __syncthreads();
  }
  if (tid < NBLK) baseR[tid] = sc[tid] - (int)cntR[tid];
  __syncthreads();
  int total = sc[NBLK - 1];
  int tcl = total > NCAP ? NCAP : total;

  int wv = tid >> 6, lane = tid & 63;
  for (int blk = wv; blk < NBLK; blk += 8) {
    int st = offR[blk], c = cntR[blk], gb = baseR[blk];
    for (int l = lane; l < c; l += 64) {
      int2 v = sorted[(long)blk * EPB + st + l];
      int gp = gb + l;
      if (gp < NCAP) gath[gp] = v;
      else {
        int oi = atomicAdd(ovfcnt, 1);
        if (oi < OVFCAP) ovf[oi] = make_int2(v.x, (b << BSH2) | v.y);
      }
    }
  }
  if (tid < BN2) deg[tid] = 0;
  __syncthreads();

  for (int k = tid; k < tcl; k += 512)
    atomicAdd(&deg[gath[k].y & (BN2 - 1)], 1);
  __syncthreads();

  sc[tid] = (tid < BN2) ? deg[tid] : 0;
  __syncthreads();
  for (int d = 1; d < 512; d <<= 1) {
    int u = (tid >= d) ? sc[tid - d] : 0;
    __syncthreads();
    sc[tid] += u;
    __syncthreads();
  }
  if (tid < BN2) {
    int excl = sc[tid] - deg[tid];
    int gpos = b * NCAP + excl;
    cur[tid] = gpos;
    int n = (b << BSH2) + tid;
    if (n < N) { noff[n] = gpos; ndeg[n] = deg[tid]; }
  }
  __syncthreads();

  for (int k = tid; k < tcl; k += 512) {
    int p = atomicAdd(&cur[gath[k].y & (BN2 - 1)], 1);
    pairs[p] = gath[k].x;
  }
}

__global__ __launch_bounds__(256) void ovf_fixup(
    const int2* __restrict__ ovf, const int* __restrict__ ovfcnt,
    const short* __restrict__ x, float* __restrict__ out) {
  int cnt = *ovfcnt;
  if (cnt > OVFCAP) cnt = OVFCAP;
  int wid = (int)((blockIdx.x * 256 + threadIdx.x) >> 6);
  int lane = threadIdx.x & 63;
  int nw = (gridDim.x * 256) >> 6;
  for (int i = wid; i < cnt; i += nw) {
    int2 e = ovf[i];
    unsigned p = (unsigned)e.x;
    float wv = (float)(p >> 17) * (1.f / 32768.f);
    float xv = bf2f(x[(long)(p & SRCMASK) * DH + lane]);
    atomicAdd(&out[(long)e.y * DH + lane], wv * xv);
  }
}

// ---------------- aggregation: 1 node/wave, ALL 16 gathers issued up front ----------------
// lane = h*16 + fj : h = edge-of-quad (0..3), fj = feature-quad (0..15).
// One coalesced pairs row load; batch-1 (edges 0..31) AND batch-2 (edges 32..63, if
// deg>32) gather instructions all issue before any accumulation -> one exposed
// latency round per node instead of two. Padded lanes hold 0 => w=0, harmless.
// FP accumulation order identical to the R5 kernel (absmax-stable).
#define ACC4(P, XV)                                          \
  do {                                                       \
    float wv_ = (float)((P) >> 17) * (1.f / 32768.f);        \
    a0 += wv_ * __uint_as_float((XV).x << 16);               \
    a1 += wv_ * __uint_as_float((XV).x & 0xFFFF0000u);       \
    a2 += wv_ * __uint_as_float((XV).y << 16);               \
    a3 += wv_ * __uint_as_float((XV).y & 0xFFFF0000u);       \
  } while (0)

__global__ __launch_bounds__(256) void agg_quad(
    const int* __restrict__ pairs, const int* __restrict__ noff,
    const int* __restrict__ ndeg,
    const uint2* __restrict__ x,   // 4×bf16 per element, 16 per node
    const float* __restrict__ bias, float* __restrict__ out, int N) {
  int wid = (int)(((long)blockIdx.x * 256 + threadIdx.x) >> 6);
  int lane = threadIdx.x & 63;
  if (wid >= N) return;
  int h = lane >> 4;        // edge within quad
  int fj = lane & 15;       // feature-quad index
  int st = noff[wid];
  int m = ndeg[wid];
  float a0 = 0.f, a1 = 0.f, a2 = 0.f, a3 = 0.f;

  int pl = (lane < m) ? pairs[st + lane] : 0;   // coalesced, padded (w=0)
  bool big = (m > 32);

  // issue ALL gathers first: batch-1 always, batch-2 when deg>32
  unsigned pg1[8], pg2[8];
  uint2 xg1[8], xg2[8];
#pragma unroll
  for (int g = 0; g < 8; ++g) pg1[g] = (unsigned)__shfl(pl, g * 4 + h);
#pragma unroll
  for (int g = 0; g < 8; ++g) xg1[g] = x[(pg1[g] & SRCMASK) * 16 + fj];
  if (big) {
#pragma unroll
    for (int g = 0; g < 8; ++g) pg2[g] = (unsigned)__shfl(pl, 32 + g * 4 + h);
#pragma unroll
    for (int g = 0; g < 8; ++g) xg2[g] = x[(pg2[g] & SRCMASK) * 16 + fj];
  }

  // accumulate batch-1 (batch-2 gathers still in flight), then batch-2
#pragma unroll
  for (int g = 0; g < 8; ++g) ACC4(pg1[g], xg1[g]);
  if (big) {
#pragma unroll
    for (int g = 0; g < 8; ++g) ACC4(pg2[g], xg2[g]);
  }

  // rare correctness tail: deg > 64
  if (m > 64) {
    for (int base = 64; base < m; base += 64) {
      int pls = (base + lane < m) ? pairs[st + base + lane] : 0;
      int mm = m - base;
      for (int q = 0; q < 64; q += 16) {
        if (q >= mm) break;
        unsigned p0 = (unsigned)__shfl(pls, q + h);
        unsigned p1 = (unsigned)__shfl(pls, q + 4 + h);
        unsigned p2 = (unsigned)__shfl(pls, q + 8 + h);
        unsigned p3 = (unsigned)__shfl(pls, q + 12 + h);
        uint2 y0 = x[(p0 & SRCMASK) * 16 + fj];
        uint2 y1 = x[(p1 & SRCMASK) * 16 + fj];
        uint2 y2 = x[(p2 & SRCMASK) * 16 + fj];
        uint2 y3 = x[(p3 & SRCMASK) * 16 + fj];
        ACC4(p0, y0); ACC4(p1, y1); ACC4(p2, y2); ACC4(p3, y3);
      }
    }
  }

  // sum over the 4 edge-groups (h); lanes with equal fj hold same features
  a0 += __shfl_xor(a0, 16); a0 += __shfl_xor(a0, 32);
  a1 += __shfl_xor(a1, 16); a1 += __shfl_xor(a1, 32);
  a2 += __shfl_xor(a2, 16); a2 += __shfl_xor(a2, 32);
  a3 += __shfl_xor(a3, 16); a3 += __shfl_xor(a3, 32);
  if (lane < 16) {
    if (bias) {
      float4 bv = ((const float4*)bias)[fj];
      a0 += bv.x; a1 += bv.y; a2 += bv.z; a3 += bv.w;
    }
    ((float4*)out)[(long)wid * 16 + fj] = make_float4(a0, a1, a2, a3);
  }
}

// ---------------- fallback kernels (R1 atomic path, f32) ----------------

__global__ __launch_bounds__(256) void gemm1_f32(
    const float* __restrict__ emb, const float* __restrict__ W1,
    float* __restrict__ x1, int N) {
  __shared__ float Ws[DIN * DH];
  __shared__ float rows[4][DIN];
  int tid = threadIdx.x;
  for (int i = tid; i < DIN * DH; i += 256) Ws[i] = W1[i];
  int r0 = blockIdx.x * 4;
  for (int i = tid; i < 4 * DIN; i += 256) {
    int rr = i >> 7, kk = i & 127;
    int r = r0 + rr;
    rows[rr][kk] = (r < N) ? emb[(long)r * DIN + kk] : 0.f;
  }
  __syncthreads();
  int rr = tid >> 6, j = tid & 63;
  int r = r0 + rr;
  float acc = 0.f;
#pragma unroll
  for (int k = 0; k < DIN; ++k) acc += rows[rr][k] * Ws[k * DH + j];
  if (r < N) x1[(long)r * DH + j] = acc;
}

__global__ __launch_bounds__(256) void gemm2_f32(
    const float* __restrict__ agg, const float* __restrict__ W2,
    const float* __restrict__ b1, float* __restrict__ x2, int N) {
  __shared__ float Ws[DH * DH];
  __shared__ float rows[4][DH];
  int tid = threadIdx.x;
  for (int i = tid; i < DH * DH; i += 256) Ws[i] = W2[i];
  int r0 = blockIdx.x * 4;
  {
    int rr = tid >> 6, kk = tid & 63;
    int r = r0 + rr;
    float v = (r < N) ? agg[(long)r * DH + kk] + b1[kk] : 0.f;
    rows[rr][kk] = v > 0.f ? v : 0.f;
  }
  __syncthreads();
  int rr = tid >> 6, j = tid & 63;
  float acc = 0.f;
#pragma unroll
  for (int k = 0; k < DH; ++k) acc += rows[rr][k] * Ws[k * DH + j];
  int r = r0 + rr;
  if (r < N) x2[(long)r * DH + j] = acc;
}

__global__ __launch_bounds__(256) void init_bias_kernel(
    float* __restrict__ out, const float* __restrict__ b2, int total) {
  int i = blockIdx.x * 256 + threadIdx.x;
  if (i < total) out[i] = b2[i & 63];
}

__global__ __launch_bounds__(256) void scatter_kernel(
    const int* __restrict__ srcs, const int* __restrict__ dsts,
    const float* __restrict__ w, const float* __restrict__ x,
    float* __restrict__ out, int E) {
  long t = (long)blockIdx.x * 256 + threadIdx.x;
  long e = t >> 6;
  if (e >= E) return;
  int j = (int)(t & 63);
  int s = srcs[e];
  int d = dsts[e];
  float val = w[e] * x[(long)s * DH + j];
  atomicAdd(&out[(long)d * DH + j], val);
}

// ---------------- host ----------------

static inline size_t align256(size_t x) { return (x + 255) & ~(size_t)255; }

extern "C" void kernel_launch(void* const* d_in, const int* in_sizes, int n_in,
                              void* d_out, int out_size, void* d_ws, size_t ws_size,
                              hipStream_t stream) {
  const int*   edge_index = (const int*)d_in[0];
  const float* edge_w     = (const float*)d_in[1];
  const float* emb        = (const float*)d_in[2];
  const float* W1         = (const float*)d_in[3];
  const float* b1         = (const float*)d_in[4];
  const float* W2         = (const float*)d_in[5];
  const float* b2         = (const float*)d_in[6];
  float* out = (float*)d_out;

  const int E = in_sizes[0] / 2;
  const int N = NNODES;
  const int* srcs = edge_index;
  const int* dsts = edge_index + E;

  const int NBLK = (E + EPB - 1) / EPB;     // 391 for E = 3.2M

  const size_t sortedbytes = (size_t)NBLK * EPB * sizeof(int2);         // 25.6 MB
  const size_t xbytes_bf   = (size_t)N * DH * sizeof(__hip_bfloat16);   // 12.8 MB
  const size_t offTabbytes = (size_t)NBLK * (NBUCK2 + 1) * sizeof(unsigned short);
  const size_t pairsbytes  = (size_t)NBUCK2 * NCAP * sizeof(int);       // 14.2 MB
  const size_t nbytes      = (size_t)N * sizeof(int);

  const int aggBlocks = (N + 3) / 4;        // 1 node per wave, 4 waves/block
  const int gemmBlocks = (N + 127) / 128;   // 128 rows per block (4 waves x 32 rows)

  size_t off = 0;
  char* base = (char*)d_ws;
  int2* sorted = (int2*)(base + off);
  off = align256(off + (sortedbytes > xbytes_bf ? sortedbytes : xbytes_bf));
  __hip_bfloat16* xbuf = (__hip_bfloat16*)sorted;  // alias: sorted dead after gather_build
  unsigned short* offTab = (unsigned short*)(base + off); off = align256(off + offTabbytes);
  int* pairs = (int*)(base + off);  off = align256(off + pairsbytes);
  int* noff  = (int*)(base + off);  off = align256(off + nbytes);
  int* ndeg  = (int*)(base + off);  off = align256(off + nbytes);
  int2* ovf  = (int2*)(base + off); off = align256(off + OVFCAP * sizeof(int2));
  int* ovfcnt = (int*)(base + off); off = align256(off + 256);
  const size_t needed_full = off;

  if (ws_size >= needed_full && NBLK <= MAXBLK) {
    // ---- 2-pass coalesced counting-sort build (once, reused by both layers) ----
    hipMemsetAsync(ovfcnt, 0, sizeof(int), stream);
    block_sort<<<NBLK, 512, 0, stream>>>(srcs, dsts, edge_w, sorted, offTab, E);
    gather_build<<<NBUCK2, 512, 0, stream>>>(offTab, sorted, noff, ndeg, pairs,
                                             ovf, ovfcnt, NBLK, N);

    // ---- layer 1: x1 = bf16(emb@W1); agg1 = A@x1 (into d_out, f32) ----
    gemm1_mfma<<<gemmBlocks, 256, 0, stream>>>(emb, W1, xbuf, N);
    agg_quad<<<aggBlocks, 256, 0, stream>>>(pairs, noff, ndeg, (const uint2*)xbuf,
                                            nullptr, out, N);
    ovf_fixup<<<8, 256, 0, stream>>>(ovf, ovfcnt, (const short*)xbuf, out);

    // ---- layer 2: x2 = bf16(relu(agg1+b1)@W2); out = A@x2 + b2 ----
    gemm2_mfma<<<gemmBlocks, 256, 0, stream>>>(out, W2, b1, xbuf, N);
    agg_quad<<<aggBlocks, 256, 0, stream>>>(pairs, noff, ndeg, (const uint2*)xbuf,
                                            b2, out, N);
    ovf_fixup<<<8, 256, 0, stream>>>(ovf, ovfcnt, (const short*)xbuf, out);
    return;
  }

  // ---- R1 fallback: atomic scatter (needs only N*64 f32) ----
  const long scatterThreads = (long)E * 64;
  const int scatterBlocks = (int)((scatterThreads + 255) / 256);
  const int rowBlocks4 = (N + 3) / 4;
  float* xb1 = (float*)d_ws;

  gemm1_f32<<<rowBlocks4, 256, 0, stream>>>(emb, W1, xb1, N);
  hipMemsetAsync(d_out, 0, (size_t)N * DH * sizeof(float), stream);
  scatter_kernel<<<scatterBlocks, 256, 0, stream>>>(srcs, dsts, edge_w, xb1, out, E);

  gemm2_f32<<<rowBlocks4, 256, 0, stream>>>(out, W2, b1, xb1, N);
  init_bias_kernel<<<(N * DH + 255) / 256, 256, 0, stream>>>(out, b2, N * DH);
  scatter_kernel<<<scatterBlocks, 256, 0, stream>>>(srcs, dsts, edge_w, xb1, out, E);
}

// Round 8
// 189.421 us; speedup vs baseline: 1.0758x; 1.0601x over previous
//
#include <hip/hip_runtime.h>
#include <hip/hip_bf16.h>

#define NNODES 100000
#define DIN 128
#define DH 64
#define SRCMASK 0x1FFFF                     // N < 2^17
#define BSH2 8
#define BN2 256                             // nodes per bucket
#define NBUCK2 ((NNODES + BN2 - 1) >> BSH2) // 391
#define NCAP 9088                           // slots per bucket (mean 8192, sigma ~90)
#define EPB 8192                            // edges per block_sort block
#define MAXBLK 512                          // max source blocks (E <= 4.19M)
#define OVFCAP 4096

typedef short s16x8 __attribute__((ext_vector_type(8)));
typedef float f32x4 __attribute__((ext_vector_type(4)));

static __device__ __forceinline__ short f2bf(float f) {
  __hip_bfloat16 h = __float2bfloat16(f);   // RTNE
  return *reinterpret_cast<short*>(&h);
}
static __device__ __forceinline__ float bf2f(short s) {
  return __uint_as_float(((unsigned)(unsigned short)s) << 16);
}

// ---------------- dense transforms via MFMA (hi/lo bf16 split ~ 17-bit mantissa) ----------------
// mfma_f32_16x16x32_bf16 layouts (m89-verified):
//   A: row = lane&15, k = (lane>>4)*8 + i
//   B: col = lane&15, k = (lane>>4)*8 + i
//   D: col = lane&15, row = (lane>>4)*4 + reg

__global__ __launch_bounds__(256, 4) void gemm1_mfma(
    const float* __restrict__ emb, const float* __restrict__ W1,
    __hip_bfloat16* __restrict__ x1, int N) {
  __shared__ short Bhi[4 * 4 * 64 * 8];   // 16 KB
  __shared__ short Blo[4 * 4 * 64 * 8];   // 16 KB
  int tid = threadIdx.x;

  for (int idx = tid; idx < 8192; idx += 256) {
    int i = idx & 7, ln = (idx >> 3) & 63, ct = (idx >> 9) & 3, kc = idx >> 11;
    int k = kc * 32 + (ln >> 4) * 8 + i;
    int col = ct * 16 + (ln & 15);
    float w = W1[k * DH + col];
    short h = f2bf(w);
    Bhi[idx] = h;
    Blo[idx] = f2bf(w - bf2f(h));
  }
  __syncthreads();

  int lane = tid & 63, wv = tid >> 6;
  int r0 = (blockIdx.x * 8 + wv * 2) * 16;
  if (r0 >= N) return;

  const int rA = lane & 15, g = lane >> 4;
  f32x4 acc[2][4] = {};

#pragma unroll
  for (int kc = 0; kc < 4; ++kc) {
    s16x8 ahi[2], alo[2];
#pragma unroll
    for (int rt = 0; rt < 2; ++rt) {
      int r = r0 + rt * 16 + rA;
      float av[8];
      if (r < N) {
        const float4* ap = (const float4*)(emb + (long)r * DIN + kc * 32 + g * 8);
        float4 v0 = ap[0], v1 = ap[1];
        av[0] = v0.x; av[1] = v0.y; av[2] = v0.z; av[3] = v0.w;
        av[4] = v1.x; av[5] = v1.y; av[6] = v1.z; av[7] = v1.w;
      } else {
#pragma unroll
        for (int i = 0; i < 8; ++i) av[i] = 0.f;
      }
#pragma unroll
      for (int i = 0; i < 8; ++i) {
        short h = f2bf(av[i]);
        ahi[rt][i] = h;
        alo[rt][i] = f2bf(av[i] - bf2f(h));
      }
    }
#pragma unroll
    for (int ct = 0; ct < 4; ++ct) {
      int fo = ((kc * 4 + ct) * 64 + lane) * 8;
      s16x8 bh = *(const s16x8*)&Bhi[fo];
      s16x8 bl = *(const s16x8*)&Blo[fo];
#pragma unroll
      for (int rt = 0; rt < 2; ++rt) {
        acc[rt][ct] = __builtin_amdgcn_mfma_f32_16x16x32_bf16(ahi[rt], bh, acc[rt][ct], 0, 0, 0);
        acc[rt][ct] = __builtin_amdgcn_mfma_f32_16x16x32_bf16(alo[rt], bh, acc[rt][ct], 0, 0, 0);
        acc[rt][ct] = __builtin_amdgcn_mfma_f32_16x16x32_bf16(ahi[rt], bl, acc[rt][ct], 0, 0, 0);
      }
    }
  }

#pragma unroll
  for (int rt = 0; rt < 2; ++rt) {
#pragma unroll
    for (int j = 0; j < 4; ++j) {
      int row = r0 + rt * 16 + g * 4 + j;
      if (row < N) {
#pragma unroll
        for (int ct = 0; ct < 4; ++ct)
          x1[(long)row * DH + ct * 16 + rA] = __float2bfloat16(acc[rt][ct][j]);
      }
    }
  }
}

__global__ __launch_bounds__(256, 4) void gemm2_mfma(
    const float* __restrict__ agg, const float* __restrict__ W2,
    const float* __restrict__ b1, __hip_bfloat16* __restrict__ x2, int N) {
  __shared__ short Bhi[2 * 4 * 64 * 8];   // 8 KB
  __shared__ short Blo[2 * 4 * 64 * 8];   // 8 KB
  int tid = threadIdx.x;

  for (int idx = tid; idx < 4096; idx += 256) {
    int i = idx & 7, ln = (idx >> 3) & 63, ct = (idx >> 9) & 3, kc = (idx >> 11) & 1;
    int k = kc * 32 + (ln >> 4) * 8 + i;
    int col = ct * 16 + (ln & 15);
    float w = W2[k * DH + col];
    short h = f2bf(w);
    Bhi[idx] = h;
    Blo[idx] = f2bf(w - bf2f(h));
  }
  __syncthreads();

  int lane = tid & 63, wv = tid >> 6;
  int r0 = (blockIdx.x * 8 + wv * 2) * 16;
  if (r0 >= N) return;

  const int rA = lane & 15, g = lane >> 4;
  f32x4 acc[2][4] = {};

#pragma unroll
  for (int kc = 0; kc < 2; ++kc) {
    const float4* bp = (const float4*)(b1 + kc * 32 + g * 8);
    float4 b0 = bp[0], b4 = bp[1];
    float bv[8] = {b0.x, b0.y, b0.z, b0.w, b4.x, b4.y, b4.z, b4.w};
    s16x8 ahi[2], alo[2];
#pragma unroll
    for (int rt = 0; rt < 2; ++rt) {
      int r = r0 + rt * 16 + rA;
      float av[8];
      if (r < N) {
        const float4* ap = (const float4*)(agg + (long)r * DH + kc * 32 + g * 8);
        float4 v0 = ap[0], v1 = ap[1];
        av[0] = v0.x; av[1] = v0.y; av[2] = v0.z; av[3] = v0.w;
        av[4] = v1.x; av[5] = v1.y; av[6] = v1.z; av[7] = v1.w;
      } else {
#pragma unroll
        for (int i = 0; i < 8; ++i) av[i] = -1e30f;  // relu() -> 0 anyway
      }
#pragma unroll
      for (int i = 0; i < 8; ++i) {
        float a = fmaxf(av[i] + bv[i], 0.f);
        short h = f2bf(a);
        ahi[rt][i] = h;
        alo[rt][i] = f2bf(a - bf2f(h));
      }
    }
#pragma unroll
    for (int ct = 0; ct < 4; ++ct) {
      int fo = ((kc * 4 + ct) * 64 + lane) * 8;
      s16x8 bh = *(const s16x8*)&Bhi[fo];
      s16x8 bl = *(const s16x8*)&Blo[fo];
#pragma unroll
      for (int rt = 0; rt < 2; ++rt) {
        acc[rt][ct] = __builtin_amdgcn_mfma_f32_16x16x32_bf16(ahi[rt], bh, acc[rt][ct], 0, 0, 0);
        acc[rt][ct] = __builtin_amdgcn_mfma_f32_16x16x32_bf16(alo[rt], bh, acc[rt][ct], 0, 0, 0);
        acc[rt][ct] = __builtin_amdgcn_mfma_f32_16x16x32_bf16(ahi[rt], bl, acc[rt][ct], 0, 0, 0);
      }
    }
  }

#pragma unroll
  for (int rt = 0; rt < 2; ++rt) {
#pragma unroll
    for (int j = 0; j < 4; ++j) {
      int row = r0 + rt * 16 + g * 4 + j;
      if (row < N) {
#pragma unroll
        for (int ct = 0; ct < 4; ++ct)
          x2[(long)row * DH + ct * 16 + rA] = __float2bfloat16(acc[rt][ct][j]);
      }
    }
  }
}

// ---------------- 2-pass counting-sort build, all global writes coalesced ----------------

__global__ __launch_bounds__(512) void block_sort(
    const int* __restrict__ srcs, const int* __restrict__ dsts,
    const float* __restrict__ w, int2* __restrict__ sorted,
    unsigned short* __restrict__ offTab, int E) {
  __shared__ int2 stage[EPB];      // 64 KB
  __shared__ int hist[512];
  __shared__ int sc[512];
  __shared__ int cur[512];
  int tid = threadIdx.x, blk = blockIdx.x;
  int e0 = blk * EPB;

  hist[tid] = 0;
  __syncthreads();

  int pk[16], bd[16];
#pragma unroll
  for (int i = 0; i < 16; ++i) {
    int e = e0 + i * 512 + tid;
    if (e < E) {
      int s = srcs[e], d = dsts[e];
      float wv = w[e];
      int q = (int)(wv * 32768.f + 0.5f);
      if (q > 32767) q = 32767;
      pk[i] = (s & SRCMASK) | (q << 17);
      bd[i] = d;
    } else bd[i] = -1;
  }
#pragma unroll
  for (int i = 0; i < 16; ++i)
    if (bd[i] >= 0) atomicAdd(&hist[bd[i] >> BSH2], 1);
  __syncthreads();

  sc[tid] = (tid < NBUCK2) ? hist[tid] : 0;
  __syncthreads();
  for (int d = 1; d < 512; d <<= 1) {
    int u = (tid >= d) ? sc[tid - d] : 0;
    __syncthreads();
    sc[tid] += u;
    __syncthreads();
  }
  long row = (long)blk * (NBUCK2 + 1);
  if (tid < NBUCK2) {
    int base = sc[tid] - hist[tid];
    cur[tid] = base;
    offTab[row + tid] = (unsigned short)base;
    if (tid == NBUCK2 - 1) offTab[row + NBUCK2] = (unsigned short)sc[tid];
  }
  __syncthreads();

#pragma unroll
  for (int i = 0; i < 16; ++i) {
    if (bd[i] >= 0) {
      int pos = atomicAdd(&cur[bd[i] >> BSH2], 1);
      stage[pos] = make_int2(pk[i], bd[i] & (BN2 - 1));
    }
  }
  __syncthreads();

  int eN = min(EPB, E - e0);
  for (int i = tid; i < eN; i += 512)
    sorted[(long)blk * EPB + i] = stage[i];   // fully coalesced
}

// ---- FUSED: blocks [0, NBLK) run the sort body; blocks [NBLK, NBLK+G1) run gemm1 ----
// LDS is a 70 KB union of the two bodies' needs. Independent inputs/outputs:
// sort reads edges -> sorted/offTab; gemm reads emb/W1 -> x1 (NOT aliased with sorted).
__global__ __launch_bounds__(512, 2) void sort_gemm1(
    const int* __restrict__ srcs, const int* __restrict__ dsts,
    const float* __restrict__ w, int2* __restrict__ sorted,
    unsigned short* __restrict__ offTab, int E,
    const float* __restrict__ emb, const float* __restrict__ W1,
    __hip_bfloat16* __restrict__ x1, int N, int NBLK, int* __restrict__ ovfcnt) {
  __shared__ __align__(16) char smem[EPB * 8 + 3 * 512 * 4];   // 71680 B
  int tid = threadIdx.x;

  if (blockIdx.x >= (unsigned)NBLK) {
    // ---------------- gemm1 body (512 threads: 8 waves x 32 rows = 256 rows) ----------------
    if (blockIdx.x == (unsigned)NBLK && tid == 0) *ovfcnt = 0;  // fold memset in
    short* Bhi = (short*)smem;          // 16 KB
    short* Blo = Bhi + 8192;            // 16 KB
    for (int idx = tid; idx < 8192; idx += 512) {
      int i = idx & 7, ln = (idx >> 3) & 63, ct = (idx >> 9) & 3, kc = idx >> 11;
      int k = kc * 32 + (ln >> 4) * 8 + i;
      int col = ct * 16 + (ln & 15);
      float wv = W1[k * DH + col];
      short h = f2bf(wv);
      Bhi[idx] = h;
      Blo[idx] = f2bf(wv - bf2f(h));
    }
    __syncthreads();

    int lane = tid & 63, wv8 = tid >> 6;
    int gblk = blockIdx.x - NBLK;
    int r0 = gblk * 256 + wv8 * 32;
    if (r0 >= N) return;

    const int rA = lane & 15, g = lane >> 4;
    f32x4 acc[2][4] = {};

#pragma unroll
    for (int kc = 0; kc < 4; ++kc) {
      s16x8 ahi[2], alo[2];
#pragma unroll
      for (int rt = 0; rt < 2; ++rt) {
        int r = r0 + rt * 16 + rA;
        float av[8];
        if (r < N) {
          const float4* ap = (const float4*)(emb + (long)r * DIN + kc * 32 + g * 8);
          float4 v0 = ap[0], v1 = ap[1];
          av[0] = v0.x; av[1] = v0.y; av[2] = v0.z; av[3] = v0.w;
          av[4] = v1.x; av[5] = v1.y; av[6] = v1.z; av[7] = v1.w;
        } else {
#pragma unroll
          for (int i = 0; i < 8; ++i) av[i] = 0.f;
        }
#pragma unroll
        for (int i = 0; i < 8; ++i) {
          short h = f2bf(av[i]);
          ahi[rt][i] = h;
          alo[rt][i] = f2bf(av[i] - bf2f(h));
        }
      }
#pragma unroll
      for (int ct = 0; ct < 4; ++ct) {
        int fo = ((kc * 4 + ct) * 64 + lane) * 8;
        s16x8 bh = *(const s16x8*)&Bhi[fo];
        s16x8 bl = *(const s16x8*)&Blo[fo];
#pragma unroll
        for (int rt = 0; rt < 2; ++rt) {
          acc[rt][ct] = __builtin_amdgcn_mfma_f32_16x16x32_bf16(ahi[rt], bh, acc[rt][ct], 0, 0, 0);
          acc[rt][ct] = __builtin_amdgcn_mfma_f32_16x16x32_bf16(alo[rt], bh, acc[rt][ct], 0, 0, 0);
          acc[rt][ct] = __builtin_amdgcn_mfma_f32_16x16x32_bf16(ahi[rt], bl, acc[rt][ct], 0, 0, 0);
        }
      }
    }

#pragma unroll
    for (int rt = 0; rt < 2; ++rt) {
#pragma unroll
      for (int j = 0; j < 4; ++j) {
        int row = r0 + rt * 16 + g * 4 + j;
        if (row < N) {
#pragma unroll
          for (int ct = 0; ct < 4; ++ct)
            x1[(long)row * DH + ct * 16 + rA] = __float2bfloat16(acc[rt][ct][j]);
        }
      }
    }
    return;
  }

  // ---------------- sort body (identical to block_sort) ----------------
  int2* stage = (int2*)smem;                 // 64 KB
  int* hist = (int*)(smem + EPB * 8);        // 2 KB
  int* sc   = hist + 512;                    // 2 KB
  int* cur  = sc + 512;                      // 2 KB
  int blk = blockIdx.x;
  int e0 = blk * EPB;

  hist[tid] = 0;
  __syncthreads();

  int pk[16], bd[16];
#pragma unroll
  for (int i = 0; i < 16; ++i) {
    int e = e0 + i * 512 + tid;
    if (e < E) {
      int s = srcs[e], d = dsts[e];
      float wv = w[e];
      int q = (int)(wv * 32768.f + 0.5f);
      if (q > 32767) q = 32767;
      pk[i] = (s & SRCMASK) | (q << 17);
      bd[i] = d;
    } else bd[i] = -1;
  }
#pragma unroll
  for (int i = 0; i < 16; ++i)
    if (bd[i] >= 0) atomicAdd(&hist[bd[i] >> BSH2], 1);
  __syncthreads();

  sc[tid] = (tid < NBUCK2) ? hist[tid] : 0;
  __syncthreads();
  for (int d = 1; d < 512; d <<= 1) {
    int u = (tid >= d) ? sc[tid - d] : 0;
    __syncthreads();
    sc[tid] += u;
    __syncthreads();
  }
  long row = (long)blk * (NBUCK2 + 1);
  if (tid < NBUCK2) {
    int base = sc[tid] - hist[tid];
    cur[tid] = base;
    offTab[row + tid] = (unsigned short)base;
    if (tid == NBUCK2 - 1) offTab[row + NBUCK2] = (unsigned short)sc[tid];
  }
  __syncthreads();

#pragma unroll
  for (int i = 0; i < 16; ++i) {
    if (bd[i] >= 0) {
      int pos = atomicAdd(&cur[bd[i] >> BSH2], 1);
      stage[pos] = make_int2(pk[i], bd[i] & (BN2 - 1));
    }
  }
  __syncthreads();

  int eN = min(EPB, E - e0);
  for (int i = tid; i < eN; i += 512)
    sorted[(long)blk * EPB + i] = stage[i];
}

__global__ __launch_bounds__(512) void gather_build(
    const unsigned short* __restrict__ offTab, const int2* __restrict__ sorted,
    int* __restrict__ noff, int* __restrict__ ndeg, int* __restrict__ pairs,
    int2* __restrict__ ovf, int* __restrict__ ovfcnt, int NBLK, int N) {
  __shared__ int2 gath[NCAP];             // 71 KB
  __shared__ unsigned short offR[MAXBLK]; // 1 KB
  __shared__ unsigned short cntR[MAXBLK]; // 1 KB
  __shared__ int baseR[MAXBLK];           // 2 KB
  __shared__ int sc[512];                 // 2 KB
  __shared__ int deg[BN2], cur[BN2];      // 2 KB
  int b = blockIdx.x, tid = threadIdx.x;

  for (int blk = tid; blk < NBLK; blk += 512) {
    long row = (long)blk * (NBUCK2 + 1);
    int st = offTab[row + b];
    int en = offTab[row + b + 1];
    offR[blk] = (unsigned short)st;
    cntR[blk] = (unsigned short)(en - st);
  }
  __syncthreads();

  sc[tid] = (tid < NBLK) ? (int)cntR[tid] : 0;
  __syncthreads();
  for (int d = 1; d < 512; d <<= 1) {
    int u = (tid >= d) ? sc[tid - d] : 0;
    __syncthreads();
    sc[tid] += u;
    __syncthreads();
  }
  if (tid < NBLK) baseR[tid] = sc[tid] - (int)cntR[tid];
  __syncthreads();
  int total = sc[NBLK - 1];
  int tcl = total > NCAP ? NCAP : total;

  int wv = tid >> 6, lane = tid & 63;
  for (int blk = wv; blk < NBLK; blk += 8) {
    int st = offR[blk], c = cntR[blk], gb = baseR[blk];
    for (int l = lane; l < c; l += 64) {
      int2 v = sorted[(long)blk * EPB + st + l];
      int gp = gb + l;
      if (gp < NCAP) gath[gp] = v;
      else {
        int oi = atomicAdd(ovfcnt, 1);
        if (oi < OVFCAP) ovf[oi] = make_int2(v.x, (b << BSH2) | v.y);
      }
    }
  }
  if (tid < BN2) deg[tid] = 0;
  __syncthreads();

  for (int k = tid; k < tcl; k += 512)
    atomicAdd(&deg[gath[k].y & (BN2 - 1)], 1);
  __syncthreads();

  sc[tid] = (tid < BN2) ? deg[tid] : 0;
  __syncthreads();
  for (int d = 1; d < 512; d <<= 1) {
    int u = (tid >= d) ? sc[tid - d] : 0;
    __syncthreads();
    sc[tid] += u;
    __syncthreads();
  }
  if (tid < BN2) {
    int excl = sc[tid] - deg[tid];
    int gpos = b * NCAP + excl;
    cur[tid] = gpos;
    int n = (b << BSH2) + tid;
    if (n < N) { noff[n] = gpos; ndeg[n] = deg[tid]; }
  }
  __syncthreads();

  for (int k = tid; k < tcl; k += 512) {
    int p = atomicAdd(&cur[gath[k].y & (BN2 - 1)], 1);
    pairs[p] = gath[k].x;
  }
}

__global__ __launch_bounds__(256) void ovf_fixup(
    const int2* __restrict__ ovf, const int* __restrict__ ovfcnt,
    const short* __restrict__ x, float* __restrict__ out) {
  int cnt = *ovfcnt;
  if (cnt > OVFCAP) cnt = OVFCAP;
  int wid = (int)((blockIdx.x * 256 + threadIdx.x) >> 6);
  int lane = threadIdx.x & 63;
  int nw = (gridDim.x * 256) >> 6;
  for (int i = wid; i < cnt; i += nw) {
    int2 e = ovf[i];
    unsigned p = (unsigned)e.x;
    float wv = (float)(p >> 17) * (1.f / 32768.f);
    float xv = bf2f(x[(long)(p & SRCMASK) * DH + lane]);
    atomicAdd(&out[(long)e.y * DH + lane], wv * xv);
  }
}

// ---------------- aggregation (exact R5 body, best measured): deep-MLP gather ----------------
#define ACC4(P, XV)                                          \
  do {                                                       \
    float wv_ = (float)((P) >> 17) * (1.f / 32768.f);        \
    a0 += wv_ * __uint_as_float((XV).x << 16);               \
    a1 += wv_ * __uint_as_float((XV).x & 0xFFFF0000u);       \
    a2 += wv_ * __uint_as_float((XV).y << 16);               \
    a3 += wv_ * __uint_as_float((XV).y & 0xFFFF0000u);       \
  } while (0)

__global__ __launch_bounds__(256) void agg_quad(
    const int* __restrict__ pairs, const int* __restrict__ noff,
    const int* __restrict__ ndeg,
    const uint2* __restrict__ x,   // 4×bf16 per element, 16 per node
    const float* __restrict__ bias, float* __restrict__ out, int N) {
  int wid = (int)(((long)blockIdx.x * 256 + threadIdx.x) >> 6);
  int lane = threadIdx.x & 63;
  if (wid >= N) return;
  int h = lane >> 4;        // edge within quad
  int fj = lane & 15;       // feature-quad index
  int st = noff[wid];
  int m = ndeg[wid];
  float a0 = 0.f, a1 = 0.f, a2 = 0.f, a3 = 0.f;

  for (int base = 0; base < m; base += 64) {
    int pl = (base + lane < m) ? pairs[st + base + lane] : 0;  // coalesced, padded
    int mm = m - base;

    unsigned pg[8];
#pragma unroll
    for (int g = 0; g < 8; ++g) pg[g] = (unsigned)__shfl(pl, g * 4 + h);
    uint2 xg[8];
#pragma unroll
    for (int g = 0; g < 8; ++g) xg[g] = x[(pg[g] & SRCMASK) * 16 + fj];
#pragma unroll
    for (int g = 0; g < 8; ++g) ACC4(pg[g], xg[g]);

#pragma unroll
    for (int q = 32; q < 64; q += 16) {
      if (q >= mm) break;
      unsigned p0 = (unsigned)__shfl(pl, q + h);
      unsigned p1 = (unsigned)__shfl(pl, q + 4 + h);
      unsigned p2 = (unsigned)__shfl(pl, q + 8 + h);
      unsigned p3 = (unsigned)__shfl(pl, q + 12 + h);
      uint2 y0 = x[(p0 & SRCMASK) * 16 + fj];
      uint2 y1 = x[(p1 & SRCMASK) * 16 + fj];
      uint2 y2 = x[(p2 & SRCMASK) * 16 + fj];
      uint2 y3 = x[(p3 & SRCMASK) * 16 + fj];
      ACC4(p0, y0); ACC4(p1, y1); ACC4(p2, y2); ACC4(p3, y3);
    }
  }

  a0 += __shfl_xor(a0, 16); a0 += __shfl_xor(a0, 32);
  a1 += __shfl_xor(a1, 16); a1 += __shfl_xor(a1, 32);
  a2 += __shfl_xor(a2, 16); a2 += __shfl_xor(a2, 32);
  a3 += __shfl_xor(a3, 16); a3 += __shfl_xor(a3, 32);
  if (lane < 16) {
    if (bias) {
      float4 bv = ((const float4*)bias)[fj];
      a0 += bv.x; a1 += bv.y; a2 += bv.z; a3 += bv.w;
    }
    ((float4*)out)[(long)wid * 16 + fj] = make_float4(a0, a1, a2, a3);
  }
}

// ---------------- fallback kernels (R1 atomic path, f32) ----------------

__global__ __launch_bounds__(256) void gemm1_f32(
    const float* __restrict__ emb, const float* __restrict__ W1,
    float* __restrict__ x1, int N) {
  __shared__ float Ws[DIN * DH];
  __shared__ float rows[4][DIN];
  int tid = threadIdx.x;
  for (int i = tid; i < DIN * DH; i += 256) Ws[i] = W1[i];
  int r0 = blockIdx.x * 4;
  for (int i = tid; i < 4 * DIN; i += 256) {
    int rr = i >> 7, kk = i & 127;
    int r = r0 + rr;
    rows[rr][kk] = (r < N) ? emb[(long)r * DIN + kk] : 0.f;
  }
  __syncthreads();
  int rr = tid >> 6, j = tid & 63;
  int r = r0 + rr;
  float acc = 0.f;
#pragma unroll
  for (int k = 0; k < DIN; ++k) acc += rows[rr][k] * Ws[k * DH + j];
  if (r < N) x1[(long)r * DH + j] = acc;
}

__global__ __launch_bounds__(256) void gemm2_f32(
    const float* __restrict__ agg, const float* __restrict__ W2,
    const float* __restrict__ b1, float* __restrict__ x2, int N) {
  __shared__ float Ws[DH * DH];
  __shared__ float rows[4][DH];
  int tid = threadIdx.x;
  for (int i = tid; i < DH * DH; i += 256) Ws[i] = W2[i];
  int r0 = blockIdx.x * 4;
  {
    int rr = tid >> 6, kk = tid & 63;
    int r = r0 + rr;
    float v = (r < N) ? agg[(long)r * DH + kk] + b1[kk] : 0.f;
    rows[rr][kk] = v > 0.f ? v : 0.f;
  }
  __syncthreads();
  int rr = tid >> 6, j = tid & 63;
  float acc = 0.f;
#pragma unroll
  for (int k = 0; k < DH; ++k) acc += rows[rr][k] * Ws[k * DH + j];
  int r = r0 + rr;
  if (r < N) x2[(long)r * DH + j] = acc;
}

__global__ __launch_bounds__(256) void init_bias_kernel(
    float* __restrict__ out, const float* __restrict__ b2, int total) {
  int i = blockIdx.x * 256 + threadIdx.x;
  if (i < total) out[i] = b2[i & 63];
}

__global__ __launch_bounds__(256) void scatter_kernel(
    const int* __restrict__ srcs, const int* __restrict__ dsts,
    const float* __restrict__ w, const float* __restrict__ x,
    float* __restrict__ out, int E) {
  long t = (long)blockIdx.x * 256 + threadIdx.x;
  long e = t >> 6;
  if (e >= E) return;
  int j = (int)(t & 63);
  int s = srcs[e];
  int d = dsts[e];
  float val = w[e] * x[(long)s * DH + j];
  atomicAdd(&out[(long)d * DH + j], val);
}

// ---------------- host ----------------

static inline size_t align256(size_t x) { return (x + 255) & ~(size_t)255; }

extern "C" void kernel_launch(void* const* d_in, const int* in_sizes, int n_in,
                              void* d_out, int out_size, void* d_ws, size_t ws_size,
                              hipStream_t stream) {
  const int*   edge_index = (const int*)d_in[0];
  const float* edge_w     = (const float*)d_in[1];
  const float* emb        = (const float*)d_in[2];
  const float* W1         = (const float*)d_in[3];
  const float* b1         = (const float*)d_in[4];
  const float* W2         = (const float*)d_in[5];
  const float* b2         = (const float*)d_in[6];
  float* out = (float*)d_out;

  const int E = in_sizes[0] / 2;
  const int N = NNODES;
  const int* srcs = edge_index;
  const int* dsts = edge_index + E;

  const int NBLK = (E + EPB - 1) / EPB;     // 391 for E = 3.2M

  const size_t sortedbytes = (size_t)NBLK * EPB * sizeof(int2);         // 25.6 MB
  const size_t xbytes_bf   = (size_t)N * DH * sizeof(__hip_bfloat16);   // 12.8 MB
  const size_t offTabbytes = (size_t)NBLK * (NBUCK2 + 1) * sizeof(unsigned short);
  const size_t pairsbytes  = (size_t)NBUCK2 * NCAP * sizeof(int);       // 14.2 MB
  const size_t nbytes      = (size_t)N * sizeof(int);

  const int aggBlocks = (N + 3) / 4;        // 1 node per wave, 4 waves/block
  const int gemmBlocks = (N + 127) / 128;   // 256-thread gemms: 128 rows/block
  const int g1Blocks   = (N + 255) / 256;   // fused 512-thread gemm1: 256 rows/block

  // ---- tier-1 layout: xbuf NOT aliased with sorted (needed for fused overlap) ----
  size_t off = 0;
  char* base = (char*)d_ws;
  int2* sorted = (int2*)(base + off);              off = align256(off + sortedbytes);
  __hip_bfloat16* xbuf = (__hip_bfloat16*)(base + off); off = align256(off + xbytes_bf);
  unsigned short* offTab = (unsigned short*)(base + off); off = align256(off + offTabbytes);
  int* pairs = (int*)(base + off);  off = align256(off + pairsbytes);
  int* noff  = (int*)(base + off);  off = align256(off + nbytes);
  int* ndeg  = (int*)(base + off);  off = align256(off + nbytes);
  int2* ovf  = (int2*)(base + off); off = align256(off + OVFCAP * sizeof(int2));
  int* ovfcnt = (int*)(base + off); off = align256(off + 256);
  const size_t needed_fused = off;

  if (ws_size >= needed_fused && NBLK <= MAXBLK) {
    // ---- build ∥ gemm1 in one dispatch; then gather; then the agg/gemm chain ----
    sort_gemm1<<<NBLK + g1Blocks, 512, 0, stream>>>(
        srcs, dsts, edge_w, sorted, offTab, E, emb, W1, xbuf, N, NBLK, ovfcnt);
    gather_build<<<NBUCK2, 512, 0, stream>>>(offTab, sorted, noff, ndeg, pairs,
                                             ovf, ovfcnt, NBLK, N);
    agg_quad<<<aggBlocks, 256, 0, stream>>>(pairs, noff, ndeg, (const uint2*)xbuf,
                                            nullptr, out, N);
    ovf_fixup<<<8, 256, 0, stream>>>(ovf, ovfcnt, (const short*)xbuf, out);
    gemm2_mfma<<<gemmBlocks, 256, 0, stream>>>(out, W2, b1, xbuf, N);
    agg_quad<<<aggBlocks, 256, 0, stream>>>(pairs, noff, ndeg, (const uint2*)xbuf,
                                            b2, out, N);
    ovf_fixup<<<8, 256, 0, stream>>>(ovf, ovfcnt, (const short*)xbuf, out);
    return;
  }

  // ---- tier-2 layout (R5-proven, xbuf aliases sorted): sequential launches ----
  off = 0;
  int2* sorted2 = (int2*)(base + off);
  off = align256(off + (sortedbytes > xbytes_bf ? sortedbytes : xbytes_bf));
  __hip_bfloat16* xbuf2 = (__hip_bfloat16*)sorted2;
  unsigned short* offTab2 = (unsigned short*)(base + off); off = align256(off + offTabbytes);
  int* pairs2 = (int*)(base + off);  off = align256(off + pairsbytes);
  int* noff2  = (int*)(base + off);  off = align256(off + nbytes);
  int* ndeg2  = (int*)(base + off);  off = align256(off + nbytes);
  int2* ovf2  = (int2*)(base + off); off = align256(off + OVFCAP * sizeof(int2));
  int* ovfcnt2 = (int*)(base + off); off = align256(off + 256);
  const size_t needed_seq = off;

  if (ws_size >= needed_seq && NBLK <= MAXBLK) {
    hipMemsetAsync(ovfcnt2, 0, sizeof(int), stream);
    block_sort<<<NBLK, 512, 0, stream>>>(srcs, dsts, edge_w, sorted2, offTab2, E);
    gather_build<<<NBUCK2, 512, 0, stream>>>(offTab2, sorted2, noff2, ndeg2, pairs2,
                                             ovf2, ovfcnt2, NBLK, N);
    gemm1_mfma<<<gemmBlocks, 256, 0, stream>>>(emb, W1, xbuf2, N);
    agg_quad<<<aggBlocks, 256, 0, stream>>>(pairs2, noff2, ndeg2, (const uint2*)xbuf2,
                                            nullptr, out, N);
    ovf_fixup<<<8, 256, 0, stream>>>(ovf2, ovfcnt2, (const short*)xbuf2, out);
    gemm2_mfma<<<gemmBlocks, 256, 0, stream>>>(out, W2, b1, xbuf2, N);
    agg_quad<<<aggBlocks, 256, 0, stream>>>(pairs2, noff2, ndeg2, (const uint2*)xbuf2,
                                            b2, out, N);
    ovf_fixup<<<8, 256, 0, stream>>>(ovf2, ovfcnt2, (const short*)xbuf2, out);
    return;
  }

  // ---- tier-3 fallback: atomic scatter (needs only N*64 f32) ----
  const long scatterThreads = (long)E * 64;
  const int scatterBlocks = (int)((scatterThreads + 255) / 256);
  const int rowBlocks4 = (N + 3) / 4;
  float* xb1 = (float*)d_ws;

  gemm1_f32<<<rowBlocks4, 256, 0, stream>>>(emb, W1, xb1, N);
  hipMemsetAsync(d_out, 0, (size_t)N * DH * sizeof(float), stream);
  scatter_kernel<<<scatterBlocks, 256, 0, stream>>>(srcs, dsts, edge_w, xb1, out, E);

  gemm2_f32<<<rowBlocks4, 256, 0, stream>>>(out, W2, b1, xb1, N);
  init_bias_kernel<<<(N * DH + 255) / 256, 256, 0, stream>>>(out, b2, N * DH);
  scatter_kernel<<<scatterBlocks, 256, 0, stream>>>(srcs, dsts, edge_w, xb1, out, E);
}

// Round 9
// 182.044 us; speedup vs baseline: 1.1194x; 1.0405x over previous
//
#include <hip/hip_runtime.h>
#include <hip/hip_bf16.h>

#define NNODES 100000
#define DIN 128
#define DH 64
#define SRCMASK 0x1FFFF                     // N < 2^17
#define BSH2 8
#define BN2 256                             // nodes per bucket
#define NBUCK2 ((NNODES + BN2 - 1) >> BSH2) // 391
#define NCAP 8960                           // slots per bucket (mean 8192 + 8.5 sigma)
#define EPB 8192                            // edges per block_sort block
#define MAXBLK 512                          // max source blocks (E <= 4.19M)
#define OVFCAP 4096

typedef short s16x8 __attribute__((ext_vector_type(8)));
typedef float f32x4 __attribute__((ext_vector_type(4)));

static __device__ __forceinline__ short f2bf(float f) {
  __hip_bfloat16 h = __float2bfloat16(f);   // RTNE
  return *reinterpret_cast<short*>(&h);
}
static __device__ __forceinline__ float bf2f(short s) {
  return __uint_as_float(((unsigned)(unsigned short)s) << 16);
}

// ---------------- dense transforms via MFMA (hi/lo bf16 split ~ 17-bit mantissa) ----------------
// mfma_f32_16x16x32_bf16 layouts (m89-verified):
//   A: row = lane&15, k = (lane>>4)*8 + i
//   B: col = lane&15, k = (lane>>4)*8 + i
//   D: col = lane&15, row = (lane>>4)*4 + reg

__global__ __launch_bounds__(256, 4) void gemm1_mfma(
    const float* __restrict__ emb, const float* __restrict__ W1,
    __hip_bfloat16* __restrict__ x1, int N) {
  __shared__ short Bhi[4 * 4 * 64 * 8];   // 16 KB
  __shared__ short Blo[4 * 4 * 64 * 8];   // 16 KB
  int tid = threadIdx.x;

  for (int idx = tid; idx < 8192; idx += 256) {
    int i = idx & 7, ln = (idx >> 3) & 63, ct = (idx >> 9) & 3, kc = idx >> 11;
    int k = kc * 32 + (ln >> 4) * 8 + i;
    int col = ct * 16 + (ln & 15);
    float w = W1[k * DH + col];
    short h = f2bf(w);
    Bhi[idx] = h;
    Blo[idx] = f2bf(w - bf2f(h));
  }
  __syncthreads();

  int lane = tid & 63, wv = tid >> 6;
  int r0 = (blockIdx.x * 8 + wv * 2) * 16;
  if (r0 >= N) return;

  const int rA = lane & 15, g = lane >> 4;
  f32x4 acc[2][4] = {};

#pragma unroll
  for (int kc = 0; kc < 4; ++kc) {
    s16x8 ahi[2], alo[2];
#pragma unroll
    for (int rt = 0; rt < 2; ++rt) {
      int r = r0 + rt * 16 + rA;
      float av[8];
      if (r < N) {
        const float4* ap = (const float4*)(emb + (long)r * DIN + kc * 32 + g * 8);
        float4 v0 = ap[0], v1 = ap[1];
        av[0] = v0.x; av[1] = v0.y; av[2] = v0.z; av[3] = v0.w;
        av[4] = v1.x; av[5] = v1.y; av[6] = v1.z; av[7] = v1.w;
      } else {
#pragma unroll
        for (int i = 0; i < 8; ++i) av[i] = 0.f;
      }
#pragma unroll
      for (int i = 0; i < 8; ++i) {
        short h = f2bf(av[i]);
        ahi[rt][i] = h;
        alo[rt][i] = f2bf(av[i] - bf2f(h));
      }
    }
#pragma unroll
    for (int ct = 0; ct < 4; ++ct) {
      int fo = ((kc * 4 + ct) * 64 + lane) * 8;
      s16x8 bh = *(const s16x8*)&Bhi[fo];
      s16x8 bl = *(const s16x8*)&Blo[fo];
#pragma unroll
      for (int rt = 0; rt < 2; ++rt) {
        acc[rt][ct] = __builtin_amdgcn_mfma_f32_16x16x32_bf16(ahi[rt], bh, acc[rt][ct], 0, 0, 0);
        acc[rt][ct] = __builtin_amdgcn_mfma_f32_16x16x32_bf16(alo[rt], bh, acc[rt][ct], 0, 0, 0);
        acc[rt][ct] = __builtin_amdgcn_mfma_f32_16x16x32_bf16(ahi[rt], bl, acc[rt][ct], 0, 0, 0);
      }
    }
  }

#pragma unroll
  for (int rt = 0; rt < 2; ++rt) {
#pragma unroll
    for (int j = 0; j < 4; ++j) {
      int row = r0 + rt * 16 + g * 4 + j;
      if (row < N) {
#pragma unroll
        for (int ct = 0; ct < 4; ++ct)
          x1[(long)row * DH + ct * 16 + rA] = __float2bfloat16(acc[rt][ct][j]);
      }
    }
  }
}

__global__ __launch_bounds__(256, 4) void gemm2_mfma(
    const float* __restrict__ agg, const float* __restrict__ W2,
    const float* __restrict__ b1, __hip_bfloat16* __restrict__ x2, int N) {
  __shared__ short Bhi[2 * 4 * 64 * 8];   // 8 KB
  __shared__ short Blo[2 * 4 * 64 * 8];   // 8 KB
  int tid = threadIdx.x;

  for (int idx = tid; idx < 4096; idx += 256) {
    int i = idx & 7, ln = (idx >> 3) & 63, ct = (idx >> 9) & 3, kc = (idx >> 11) & 1;
    int k = kc * 32 + (ln >> 4) * 8 + i;
    int col = ct * 16 + (ln & 15);
    float w = W2[k * DH + col];
    short h = f2bf(w);
    Bhi[idx] = h;
    Blo[idx] = f2bf(w - bf2f(h));
  }
  __syncthreads();

  int lane = tid & 63, wv = tid >> 6;
  int r0 = (blockIdx.x * 8 + wv * 2) * 16;
  if (r0 >= N) return;

  const int rA = lane & 15, g = lane >> 4;
  f32x4 acc[2][4] = {};

#pragma unroll
  for (int kc = 0; kc < 2; ++kc) {
    const float4* bp = (const float4*)(b1 + kc * 32 + g * 8);
    float4 b0 = bp[0], b4 = bp[1];
    float bv[8] = {b0.x, b0.y, b0.z, b0.w, b4.x, b4.y, b4.z, b4.w};
    s16x8 ahi[2], alo[2];
#pragma unroll
    for (int rt = 0; rt < 2; ++rt) {
      int r = r0 + rt * 16 + rA;
      float av[8];
      if (r < N) {
        const float4* ap = (const float4*)(agg + (long)r * DH + kc * 32 + g * 8);
        float4 v0 = ap[0], v1 = ap[1];
        av[0] = v0.x; av[1] = v0.y; av[2] = v0.z; av[3] = v0.w;
        av[4] = v1.x; av[5] = v1.y; av[6] = v1.z; av[7] = v1.w;
      } else {
#pragma unroll
        for (int i = 0; i < 8; ++i) av[i] = -1e30f;  // relu() -> 0 anyway
      }
#pragma unroll
      for (int i = 0; i < 8; ++i) {
        float a = fmaxf(av[i] + bv[i], 0.f);
        short h = f2bf(a);
        ahi[rt][i] = h;
        alo[rt][i] = f2bf(a - bf2f(h));
      }
    }
#pragma unroll
    for (int ct = 0; ct < 4; ++ct) {
      int fo = ((kc * 4 + ct) * 64 + lane) * 8;
      s16x8 bh = *(const s16x8*)&Bhi[fo];
      s16x8 bl = *(const s16x8*)&Blo[fo];
#pragma unroll
      for (int rt = 0; rt < 2; ++rt) {
        acc[rt][ct] = __builtin_amdgcn_mfma_f32_16x16x32_bf16(ahi[rt], bh, acc[rt][ct], 0, 0, 0);
        acc[rt][ct] = __builtin_amdgcn_mfma_f32_16x16x32_bf16(alo[rt], bh, acc[rt][ct], 0, 0, 0);
        acc[rt][ct] = __builtin_amdgcn_mfma_f32_16x16x32_bf16(ahi[rt], bl, acc[rt][ct], 0, 0, 0);
      }
    }
  }

#pragma unroll
  for (int rt = 0; rt < 2; ++rt) {
#pragma unroll
    for (int j = 0; j < 4; ++j) {
      int row = r0 + rt * 16 + g * 4 + j;
      if (row < N) {
#pragma unroll
        for (int ct = 0; ct < 4; ++ct)
          x2[(long)row * DH + ct * 16 + rA] = __float2bfloat16(acc[rt][ct][j]);
      }
    }
  }
}

// ---------------- 2-pass counting-sort build: split pk/dlow arrays, coalesced writes ---------

__global__ __launch_bounds__(512, 6) void block_sort(
    const int* __restrict__ srcs, const int* __restrict__ dsts,
    const float* __restrict__ w, int* __restrict__ spk,
    unsigned char* __restrict__ sdl, unsigned short* __restrict__ offTab, int E) {
  __shared__ int stageP[EPB];             // 32 KB
  __shared__ unsigned char stageD[EPB];   // 8 KB
  __shared__ int hist[512];
  __shared__ int sc[512];
  __shared__ int cur[512];
  int tid = threadIdx.x, blk = blockIdx.x;
  int e0 = blk * EPB;

  hist[tid] = 0;
  __syncthreads();

  int pk[16], bd[16];
#pragma unroll
  for (int i = 0; i < 16; ++i) {
    int e = e0 + i * 512 + tid;
    if (e < E) {
      int s = srcs[e], d = dsts[e];
      float wv = w[e];
      int q = (int)(wv * 32768.f + 0.5f);
      if (q > 32767) q = 32767;
      pk[i] = (s & SRCMASK) | (q << 17);
      bd[i] = d;
    } else bd[i] = -1;
  }
#pragma unroll
  for (int i = 0; i < 16; ++i)
    if (bd[i] >= 0) atomicAdd(&hist[bd[i] >> BSH2], 1);
  __syncthreads();

  sc[tid] = (tid < NBUCK2) ? hist[tid] : 0;
  __syncthreads();
  for (int d = 1; d < 512; d <<= 1) {
    int u = (tid >= d) ? sc[tid - d] : 0;
    __syncthreads();
    sc[tid] += u;
    __syncthreads();
  }
  long row = (long)blk * (NBUCK2 + 1);
  if (tid < NBUCK2) {
    int base = sc[tid] - hist[tid];
    cur[tid] = base;
    offTab[row + tid] = (unsigned short)base;
    if (tid == NBUCK2 - 1) offTab[row + NBUCK2] = (unsigned short)sc[tid];
  }
  __syncthreads();

#pragma unroll
  for (int i = 0; i < 16; ++i) {
    if (bd[i] >= 0) {
      int pos = atomicAdd(&cur[bd[i] >> BSH2], 1);
      stageP[pos] = pk[i];
      stageD[pos] = (unsigned char)(bd[i] & (BN2 - 1));
    }
  }
  __syncthreads();

  int eN = min(EPB, E - e0);
  for (int i = tid; i < eN; i += 512) {
    spk[(long)blk * EPB + i] = stageP[i];   // fully coalesced
    sdl[(long)blk * EPB + i] = stageD[i];
  }
}

// ---- FUSED: blocks [0, NBLK) run the sort body; blocks [NBLK, NBLK+G1) run gemm1 ----
// smem union: sort = stageP 32K + stageD 8K + hist/sc/cur 6K = 46 KB; gemm = 32 KB.
__global__ __launch_bounds__(512, 6) void sort_gemm1(
    const int* __restrict__ srcs, const int* __restrict__ dsts,
    const float* __restrict__ w, int* __restrict__ spk,
    unsigned char* __restrict__ sdl, unsigned short* __restrict__ offTab, int E,
    const float* __restrict__ emb, const float* __restrict__ W1,
    __hip_bfloat16* __restrict__ x1, int N, int NBLK, int* __restrict__ ovfcnt) {
  __shared__ __align__(16) char smem[EPB * 4 + EPB + 3 * 512 * 4];   // 47104 B
  int tid = threadIdx.x;

  if (blockIdx.x >= (unsigned)NBLK) {
    // ---------------- gemm1 body (512 threads: 8 waves x 32 rows = 256 rows) ----------------
    if (blockIdx.x == (unsigned)NBLK && tid == 0) *ovfcnt = 0;  // fold memset in
    short* Bhi = (short*)smem;          // 16 KB
    short* Blo = Bhi + 8192;            // 16 KB
    for (int idx = tid; idx < 8192; idx += 512) {
      int i = idx & 7, ln = (idx >> 3) & 63, ct = (idx >> 9) & 3, kc = idx >> 11;
      int k = kc * 32 + (ln >> 4) * 8 + i;
      int col = ct * 16 + (ln & 15);
      float wv = W1[k * DH + col];
      short h = f2bf(wv);
      Bhi[idx] = h;
      Blo[idx] = f2bf(wv - bf2f(h));
    }
    __syncthreads();

    int lane = tid & 63, wv8 = tid >> 6;
    int gblk = blockIdx.x - NBLK;
    int r0 = gblk * 256 + wv8 * 32;
    if (r0 >= N) return;

    const int rA = lane & 15, g = lane >> 4;
    f32x4 acc[2][4] = {};

#pragma unroll
    for (int kc = 0; kc < 4; ++kc) {
      s16x8 ahi[2], alo[2];
#pragma unroll
      for (int rt = 0; rt < 2; ++rt) {
        int r = r0 + rt * 16 + rA;
        float av[8];
        if (r < N) {
          const float4* ap = (const float4*)(emb + (long)r * DIN + kc * 32 + g * 8);
          float4 v0 = ap[0], v1 = ap[1];
          av[0] = v0.x; av[1] = v0.y; av[2] = v0.z; av[3] = v0.w;
          av[4] = v1.x; av[5] = v1.y; av[6] = v1.z; av[7] = v1.w;
        } else {
#pragma unroll
          for (int i = 0; i < 8; ++i) av[i] = 0.f;
        }
#pragma unroll
        for (int i = 0; i < 8; ++i) {
          short h = f2bf(av[i]);
          ahi[rt][i] = h;
          alo[rt][i] = f2bf(av[i] - bf2f(h));
        }
      }
#pragma unroll
      for (int ct = 0; ct < 4; ++ct) {
        int fo = ((kc * 4 + ct) * 64 + lane) * 8;
        s16x8 bh = *(const s16x8*)&Bhi[fo];
        s16x8 bl = *(const s16x8*)&Blo[fo];
#pragma unroll
        for (int rt = 0; rt < 2; ++rt) {
          acc[rt][ct] = __builtin_amdgcn_mfma_f32_16x16x32_bf16(ahi[rt], bh, acc[rt][ct], 0, 0, 0);
          acc[rt][ct] = __builtin_amdgcn_mfma_f32_16x16x32_bf16(alo[rt], bh, acc[rt][ct], 0, 0, 0);
          acc[rt][ct] = __builtin_amdgcn_mfma_f32_16x16x32_bf16(ahi[rt], bl, acc[rt][ct], 0, 0, 0);
        }
      }
    }

#pragma unroll
    for (int rt = 0; rt < 2; ++rt) {
#pragma unroll
      for (int j = 0; j < 4; ++j) {
        int row = r0 + rt * 16 + g * 4 + j;
        if (row < N) {
#pragma unroll
          for (int ct = 0; ct < 4; ++ct)
            x1[(long)row * DH + ct * 16 + rA] = __float2bfloat16(acc[rt][ct][j]);
        }
      }
    }
    return;
  }

  // ---------------- sort body (identical to block_sort) ----------------
  int* stageP = (int*)smem;                               // 32 KB
  unsigned char* stageD = (unsigned char*)(smem + EPB * 4);  // 8 KB
  int* hist = (int*)(smem + EPB * 4 + EPB);               // 2 KB
  int* sc   = hist + 512;                                 // 2 KB
  int* cur  = sc + 512;                                   // 2 KB
  int blk = blockIdx.x;
  int e0 = blk * EPB;

  hist[tid] = 0;
  __syncthreads();

  int pk[16], bd[16];
#pragma unroll
  for (int i = 0; i < 16; ++i) {
    int e = e0 + i * 512 + tid;
    if (e < E) {
      int s = srcs[e], d = dsts[e];
      float wv = w[e];
      int q = (int)(wv * 32768.f + 0.5f);
      if (q > 32767) q = 32767;
      pk[i] = (s & SRCMASK) | (q << 17);
      bd[i] = d;
    } else bd[i] = -1;
  }
#pragma unroll
  for (int i = 0; i < 16; ++i)
    if (bd[i] >= 0) atomicAdd(&hist[bd[i] >> BSH2], 1);
  __syncthreads();

  sc[tid] = (tid < NBUCK2) ? hist[tid] : 0;
  __syncthreads();
  for (int d = 1; d < 512; d <<= 1) {
    int u = (tid >= d) ? sc[tid - d] : 0;
    __syncthreads();
    sc[tid] += u;
    __syncthreads();
  }
  long row = (long)blk * (NBUCK2 + 1);
  if (tid < NBUCK2) {
    int base = sc[tid] - hist[tid];
    cur[tid] = base;
    offTab[row + tid] = (unsigned short)base;
    if (tid == NBUCK2 - 1) offTab[row + NBUCK2] = (unsigned short)sc[tid];
  }
  __syncthreads();

#pragma unroll
  for (int i = 0; i < 16; ++i) {
    if (bd[i] >= 0) {
      int pos = atomicAdd(&cur[bd[i] >> BSH2], 1);
      stageP[pos] = pk[i];
      stageD[pos] = (unsigned char)(bd[i] & (BN2 - 1));
    }
  }
  __syncthreads();

  int eN = min(EPB, E - e0);
  for (int i = tid; i < eN; i += 512) {
    spk[(long)blk * EPB + i] = stageP[i];
    sdl[(long)blk * EPB + i] = stageD[i];
  }
}

// Pass 2: one block per bucket; balanced flattened chunk copy via binary search.
__global__ __launch_bounds__(512, 6) void gather_build(
    const unsigned short* __restrict__ offTab, const int* __restrict__ spk,
    const unsigned char* __restrict__ sdl,
    int* __restrict__ noff, int* __restrict__ ndeg, int* __restrict__ pairs,
    int2* __restrict__ ovf, int* __restrict__ ovfcnt, int NBLK, int N) {
  __shared__ int gathP[NCAP];             // 35 KB
  __shared__ unsigned char gathD[NCAP];   // 8.75 KB
  __shared__ unsigned short offR[MAXBLK]; // 1 KB
  __shared__ unsigned short cntR[MAXBLK]; // 1 KB
  __shared__ int baseR[MAXBLK];           // 2 KB
  __shared__ int sc[512];                 // 2 KB
  __shared__ int deg[BN2], cur[BN2];      // 2 KB
  int b = blockIdx.x, tid = threadIdx.x;

  for (int blk = tid; blk < NBLK; blk += 512) {
    long row = (long)blk * (NBUCK2 + 1);
    int st = offTab[row + b];
    int en = offTab[row + b + 1];
    offR[blk] = (unsigned short)st;
    cntR[blk] = (unsigned short)(en - st);
  }
  __syncthreads();

  sc[tid] = (tid < NBLK) ? (int)cntR[tid] : 0;
  __syncthreads();
  for (int d = 1; d < 512; d <<= 1) {
    int u = (tid >= d) ? sc[tid - d] : 0;
    __syncthreads();
    sc[tid] += u;
    __syncthreads();
  }
  if (tid < NBLK) baseR[tid] = sc[tid] - (int)cntR[tid];
  __syncthreads();
  int total = sc[NBLK - 1];
  int tcl = total > NCAP ? NCAP : total;

  // balanced copy: thread owns global slot g; binary search for source chunk
  for (int g = tid; g < total; g += 512) {
    int lo = 0, hi = NBLK - 1;
    while (lo < hi) {
      int mid = (lo + hi + 1) >> 1;
      if (baseR[mid] <= g) lo = mid; else hi = mid - 1;
    }
    int pos = (int)offR[lo] + (g - baseR[lo]);
    int pk = spk[(long)lo * EPB + pos];
    int dl = sdl[(long)lo * EPB + pos];
    if (g < NCAP) {
      gathP[g] = pk;
      gathD[g] = (unsigned char)dl;
    } else {
      int oi = atomicAdd(ovfcnt, 1);
      if (oi < OVFCAP) ovf[oi] = make_int2(pk, (b << BSH2) | dl);
    }
  }
  if (tid < BN2) deg[tid] = 0;
  __syncthreads();

  for (int k = tid; k < tcl; k += 512)
    atomicAdd(&deg[gathD[k]], 1);
  __syncthreads();

  sc[tid] = (tid < BN2) ? deg[tid] : 0;
  __syncthreads();
  for (int d = 1; d < 512; d <<= 1) {
    int u = (tid >= d) ? sc[tid - d] : 0;
    __syncthreads();
    sc[tid] += u;
    __syncthreads();
  }
  if (tid < BN2) {
    int excl = sc[tid] - deg[tid];
    int gpos = b * NCAP + excl;
    cur[tid] = gpos;
    int n = (b << BSH2) + tid;
    if (n < N) { noff[n] = gpos; ndeg[n] = deg[tid]; }
  }
  __syncthreads();

  for (int k = tid; k < tcl; k += 512) {
    int p = atomicAdd(&cur[gathD[k]], 1);
    pairs[p] = gathP[k];
  }
}

__global__ __launch_bounds__(256) void ovf_fixup(
    const int2* __restrict__ ovf, const int* __restrict__ ovfcnt,
    const short* __restrict__ x, float* __restrict__ out) {
  int cnt = *ovfcnt;
  if (cnt > OVFCAP) cnt = OVFCAP;
  int wid = (int)((blockIdx.x * 256 + threadIdx.x) >> 6);
  int lane = threadIdx.x & 63;
  int nw = (gridDim.x * 256) >> 6;
  for (int i = wid; i < cnt; i += nw) {
    int2 e = ovf[i];
    unsigned p = (unsigned)e.x;
    float wv = (float)(p >> 17) * (1.f / 32768.f);
    float xv = bf2f(x[(long)(p & SRCMASK) * DH + lane]);
    atomicAdd(&out[(long)e.y * DH + lane], wv * xv);
  }
}

// ---------------- aggregation (exact R5 body, best measured): deep-MLP gather ----------------
#define ACC4(P, XV)                                          \
  do {                                                       \
    float wv_ = (float)((P) >> 17) * (1.f / 32768.f);        \
    a0 += wv_ * __uint_as_float((XV).x << 16);               \
    a1 += wv_ * __uint_as_float((XV).x & 0xFFFF0000u);       \
    a2 += wv_ * __uint_as_float((XV).y << 16);               \
    a3 += wv_ * __uint_as_float((XV).y & 0xFFFF0000u);       \
  } while (0)

__global__ __launch_bounds__(256) void agg_quad(
    const int* __restrict__ pairs, const int* __restrict__ noff,
    const int* __restrict__ ndeg,
    const uint2* __restrict__ x,   // 4×bf16 per element, 16 per node
    const float* __restrict__ bias, float* __restrict__ out, int N) {
  int wid = (int)(((long)blockIdx.x * 256 + threadIdx.x) >> 6);
  int lane = threadIdx.x & 63;
  if (wid >= N) return;
  int h = lane >> 4;        // edge within quad
  int fj = lane & 15;       // feature-quad index
  int st = noff[wid];
  int m = ndeg[wid];
  float a0 = 0.f, a1 = 0.f, a2 = 0.f, a3 = 0.f;

  for (int base = 0; base < m; base += 64) {
    int pl = (base + lane < m) ? pairs[st + base + lane] : 0;  // coalesced, padded
    int mm = m - base;

    unsigned pg[8];
#pragma unroll
    for (int g = 0; g < 8; ++g) pg[g] = (unsigned)__shfl(pl, g * 4 + h);
    uint2 xg[8];
#pragma unroll
    for (int g = 0; g < 8; ++g) xg[g] = x[(pg[g] & SRCMASK) * 16 + fj];
#pragma unroll
    for (int g = 0; g < 8; ++g) ACC4(pg[g], xg[g]);

#pragma unroll
    for (int q = 32; q < 64; q += 16) {
      if (q >= mm) break;
      unsigned p0 = (unsigned)__shfl(pl, q + h);
      unsigned p1 = (unsigned)__shfl(pl, q + 4 + h);
      unsigned p2 = (unsigned)__shfl(pl, q + 8 + h);
      unsigned p3 = (unsigned)__shfl(pl, q + 12 + h);
      uint2 y0 = x[(p0 & SRCMASK) * 16 + fj];
      uint2 y1 = x[(p1 & SRCMASK) * 16 + fj];
      uint2 y2 = x[(p2 & SRCMASK) * 16 + fj];
      uint2 y3 = x[(p3 & SRCMASK) * 16 + fj];
      ACC4(p0, y0); ACC4(p1, y1); ACC4(p2, y2); ACC4(p3, y3);
    }
  }

  a0 += __shfl_xor(a0, 16); a0 += __shfl_xor(a0, 32);
  a1 += __shfl_xor(a1, 16); a1 += __shfl_xor(a1, 32);
  a2 += __shfl_xor(a2, 16); a2 += __shfl_xor(a2, 32);
  a3 += __shfl_xor(a3, 16); a3 += __shfl_xor(a3, 32);
  if (lane < 16) {
    if (bias) {
      float4 bv = ((const float4*)bias)[fj];
      a0 += bv.x; a1 += bv.y; a2 += bv.z; a3 += bv.w;
    }
    ((float4*)out)[(long)wid * 16 + fj] = make_float4(a0, a1, a2, a3);
  }
}

// ---------------- fallback kernels (R1 atomic path, f32) ----------------

__global__ __launch_bounds__(256) void gemm1_f32(
    const float* __restrict__ emb, const float* __restrict__ W1,
    float* __restrict__ x1, int N) {
  __shared__ float Ws[DIN * DH];
  __shared__ float rows[4][DIN];
  int tid = threadIdx.x;
  for (int i = tid; i < DIN * DH; i += 256) Ws[i] = W1[i];
  int r0 = blockIdx.x * 4;
  for (int i = tid; i < 4 * DIN; i += 256) {
    int rr = i >> 7, kk = i & 127;
    int r = r0 + rr;
    rows[rr][kk] = (r < N) ? emb[(long)r * DIN + kk] : 0.f;
  }
  __syncthreads();
  int rr = tid >> 6, j = tid & 63;
  int r = r0 + rr;
  float acc = 0.f;
#pragma unroll
  for (int k = 0; k < DIN; ++k) acc += rows[rr][k] * Ws[k * DH + j];
  if (r < N) x1[(long)r * DH + j] = acc;
}

__global__ __launch_bounds__(256) void gemm2_f32(
    const float* __restrict__ agg, const float* __restrict__ W2,
    const float* __restrict__ b1, float* __restrict__ x2, int N) {
  __shared__ float Ws[DH * DH];
  __shared__ float rows[4][DH];
  int tid = threadIdx.x;
  for (int i = tid; i < DH * DH; i += 256) Ws[i] = W2[i];
  int r0 = blockIdx.x * 4;
  {
    int rr = tid >> 6, kk = tid & 63;
    int r = r0 + rr;
    float v = (r < N) ? agg[(long)r * DH + kk] + b1[kk] : 0.f;
    rows[rr][kk] = v > 0.f ? v : 0.f;
  }
  __syncthreads();
  int rr = tid >> 6, j = tid & 63;
  float acc = 0.f;
#pragma unroll
  for (int k = 0; k < DH; ++k) acc += rows[rr][k] * Ws[k * DH + j];
  int r = r0 + rr;
  if (r < N) x2[(long)r * DH + j] = acc;
}

__global__ __launch_bounds__(256) void init_bias_kernel(
    float* __restrict__ out, const float* __restrict__ b2, int total) {
  int i = blockIdx.x * 256 + threadIdx.x;
  if (i < total) out[i] = b2[i & 63];
}

__global__ __launch_bounds__(256) void scatter_kernel(
    const int* __restrict__ srcs, const int* __restrict__ dsts,
    const float* __restrict__ w, const float* __restrict__ x,
    float* __restrict__ out, int E) {
  long t = (long)blockIdx.x * 256 + threadIdx.x;
  long e = t >> 6;
  if (e >= E) return;
  int j = (int)(t & 63);
  int s = srcs[e];
  int d = dsts[e];
  float val = w[e] * x[(long)s * DH + j];
  atomicAdd(&out[(long)d * DH + j], val);
}

// ---------------- host ----------------

static inline size_t align256(size_t x) { return (x + 255) & ~(size_t)255; }

extern "C" void kernel_launch(void* const* d_in, const int* in_sizes, int n_in,
                              void* d_out, int out_size, void* d_ws, size_t ws_size,
                              hipStream_t stream) {
  const int*   edge_index = (const int*)d_in[0];
  const float* edge_w     = (const float*)d_in[1];
  const float* emb        = (const float*)d_in[2];
  const float* W1         = (const float*)d_in[3];
  const float* b1         = (const float*)d_in[4];
  const float* W2         = (const float*)d_in[5];
  const float* b2         = (const float*)d_in[6];
  float* out = (float*)d_out;

  const int E = in_sizes[0] / 2;
  const int N = NNODES;
  const int* srcs = edge_index;
  const int* dsts = edge_index + E;

  const int NBLK = (E + EPB - 1) / EPB;     // 391 for E = 3.2M

  const size_t spkbytes    = (size_t)NBLK * EPB * sizeof(int);          // 12.8 MB
  const size_t sdlbytes    = (size_t)NBLK * EPB;                        // 3.2 MB
  const size_t xbytes_bf   = (size_t)N * DH * sizeof(__hip_bfloat16);   // 12.8 MB
  const size_t offTabbytes = (size_t)NBLK * (NBUCK2 + 1) * sizeof(unsigned short);
  const size_t pairsbytes  = (size_t)NBUCK2 * NCAP * sizeof(int);       // 14.0 MB
  const size_t nbytes      = (size_t)N * sizeof(int);

  const int aggBlocks = (N + 3) / 4;        // 1 node per wave, 4 waves/block
  const int gemmBlocks = (N + 127) / 128;   // 256-thread gemms: 128 rows/block
  const int g1Blocks   = (N + 255) / 256;   // fused 512-thread gemm1: 256 rows/block

  // ---- tier-1 layout: xbuf NOT aliased with spk (needed for fused overlap) ----
  size_t off = 0;
  char* base = (char*)d_ws;
  int* spk = (int*)(base + off);                   off = align256(off + spkbytes);
  unsigned char* sdl = (unsigned char*)(base + off); off = align256(off + sdlbytes);
  __hip_bfloat16* xbuf = (__hip_bfloat16*)(base + off); off = align256(off + xbytes_bf);
  unsigned short* offTab = (unsigned short*)(base + off); off = align256(off + offTabbytes);
  int* pairs = (int*)(base + off);  off = align256(off + pairsbytes);
  int* noff  = (int*)(base + off);  off = align256(off + nbytes);
  int* ndeg  = (int*)(base + off);  off = align256(off + nbytes);
  int2* ovf  = (int2*)(base + off); off = align256(off + OVFCAP * sizeof(int2));
  int* ovfcnt = (int*)(base + off); off = align256(off + 256);
  const size_t needed_fused = off;

  if (ws_size >= needed_fused && NBLK <= MAXBLK) {
    // ---- build ∥ gemm1 in one dispatch; then gather; then the agg/gemm chain ----
    sort_gemm1<<<NBLK + g1Blocks, 512, 0, stream>>>(
        srcs, dsts, edge_w, spk, sdl, offTab, E, emb, W1, xbuf, N, NBLK, ovfcnt);
    gather_build<<<NBUCK2, 512, 0, stream>>>(offTab, spk, sdl, noff, ndeg, pairs,
                                             ovf, ovfcnt, NBLK, N);
    agg_quad<<<aggBlocks, 256, 0, stream>>>(pairs, noff, ndeg, (const uint2*)xbuf,
                                            nullptr, out, N);
    ovf_fixup<<<8, 256, 0, stream>>>(ovf, ovfcnt, (const short*)xbuf, out);
    gemm2_mfma<<<gemmBlocks, 256, 0, stream>>>(out, W2, b1, xbuf, N);
    agg_quad<<<aggBlocks, 256, 0, stream>>>(pairs, noff, ndeg, (const uint2*)xbuf,
                                            b2, out, N);
    ovf_fixup<<<8, 256, 0, stream>>>(ovf, ovfcnt, (const short*)xbuf, out);
    return;
  }

  // ---- tier-2 layout (xbuf aliases spk): sequential launches ----
  off = 0;
  int* spk2 = (int*)(base + off);
  off = align256(off + (spkbytes > xbytes_bf ? spkbytes : xbytes_bf));
  __hip_bfloat16* xbuf2 = (__hip_bfloat16*)spk2;
  unsigned char* sdl2 = (unsigned char*)(base + off); off = align256(off + sdlbytes);
  unsigned short* offTab2 = (unsigned short*)(base + off); off = align256(off + offTabbytes);
  int* pairs2 = (int*)(base + off);  off = align256(off + pairsbytes);
  int* noff2  = (int*)(base + off);  off = align256(off + nbytes);
  int* ndeg2  = (int*)(base + off);  off = align256(off + nbytes);
  int2* ovf2  = (int2*)(base + off); off = align256(off + OVFCAP * sizeof(int2));
  int* ovfcnt2 = (int*)(base + off); off = align256(off + 256);
  const size_t needed_seq = off;

  if (ws_size >= needed_seq && NBLK <= MAXBLK) {
    hipMemsetAsync(ovfcnt2, 0, sizeof(int), stream);
    block_sort<<<NBLK, 512, 0, stream>>>(srcs, dsts, edge_w, spk2, sdl2, offTab2, E);
    gather_build<<<NBUCK2, 512, 0, stream>>>(offTab2, spk2, sdl2, noff2, ndeg2, pairs2,
                                             ovf2, ovfcnt2, NBLK, N);
    gemm1_mfma<<<gemmBlocks, 256, 0, stream>>>(emb, W1, xbuf2, N);
    agg_quad<<<aggBlocks, 256, 0, stream>>>(pairs2, noff2, ndeg2, (const uint2*)xbuf2,
                                            nullptr, out, N);
    ovf_fixup<<<8, 256, 0, stream>>>(ovf2, ovfcnt2, (const short*)xbuf2, out);
    gemm2_mfma<<<gemmBlocks, 256, 0, stream>>>(out, W2, b1, xbuf2, N);
    agg_quad<<<aggBlocks, 256, 0, stream>>>(pairs2, noff2, ndeg2, (const uint2*)xbuf2,
                                            b2, out, N);
    ovf_fixup<<<8, 256, 0, stream>>>(ovf2, ovfcnt2, (const short*)xbuf2, out);
    return;
  }

  // ---- tier-3 fallback: atomic scatter (needs only N*64 f32) ----
  const long scatterThreads = (long)E * 64;
  const int scatterBlocks = (int)((scatterThreads + 255) / 256);
  const int rowBlocks4 = (N + 3) / 4;
  float* xb1 = (float*)d_ws;

  gemm1_f32<<<rowBlocks4, 256, 0, stream>>>(emb, W1, xb1, N);
  hipMemsetAsync(d_out, 0, (size_t)N * DH * sizeof(float), stream);
  scatter_kernel<<<scatterBlocks, 256, 0, stream>>>(srcs, dsts, edge_w, xb1, out, E);

  gemm2_f32<<<rowBlocks4, 256, 0, stream>>>(out, W2, b1, xb1, N);
  init_bias_kernel<<<(N * DH + 255) / 256, 256, 0, stream>>>(out, b2, N * DH);
  scatter_kernel<<<scatterBlocks, 256, 0, stream>>>(srcs, dsts, edge_w, xb1, out, E);
}